// Round 19
// baseline (643.112 us; speedup 1.0000x reference)
//
#include <hip/hip_runtime.h>
#include <hip/hip_bf16.h>

#define N_NODES 200000
#define N_EDGES 800000
#define N_MOL   10000
#define HDIM    64
#define EDGE_DIM 16
#define BN_EPS 1e-5f
#define SCAN_BLOCKS ((N_NODES + 255) / 256)   // 782

typedef __attribute__((ext_vector_type(8))) short short8;
typedef __attribute__((ext_vector_type(4))) float f32x4;

// ---------------------------------------------------------------------------
// bf16 helpers
// ---------------------------------------------------------------------------
__device__ __forceinline__ unsigned int pk2(float a, float b) {
    __hip_bfloat162 h = __float22bfloat162_rn(make_float2(a, b));
    union { __hip_bfloat162 h; unsigned int u; } c;
    c.h = h;
    return c.u;
}
__device__ __forceinline__ short8 cvt8(float4 a, float4 b) {
    union { short8 s; unsigned int u[4]; } r;
    r.u[0] = pk2(a.x, a.y); r.u[1] = pk2(a.z, a.w);
    r.u[2] = pk2(b.x, b.y); r.u[3] = pk2(b.z, b.w);
    return r.s;
}
__device__ __forceinline__ float bf2f(unsigned short u) {
    return __uint_as_float(((unsigned int)u) << 16);
}
__device__ __forceinline__ unsigned short f2bf(float a) {
    union { __hip_bfloat16 h; unsigned short u; } c;
    c.h = __float2bfloat16(a);
    return c.u;
}
__device__ __forceinline__ float4 bf4f(ushort4 u) {
    return make_float4(bf2f(u.x), bf2f(u.y), bf2f(u.z), bf2f(u.w));
}

// ---------------------------------------------------------------------------
// x -> bf16 copy (layer-1 gather source)
// ---------------------------------------------------------------------------
__global__ __launch_bounds__(256) void cvtx_kernel(
    const float* __restrict__ x, unsigned short* __restrict__ xb)
{
    int i = blockIdx.x * 256 + threadIdx.x;
    if ((size_t)i * 4 >= (size_t)N_NODES * 40) return;
    float4 v = *(const float4*)(x + (size_t)i * 4);
    union { ushort4 s; unsigned int u[2]; } r;
    r.u[0] = pk2(v.x, v.y); r.u[1] = pk2(v.z, v.w);
    *(ushort4*)(xb + (size_t)i * 4) = r.s;
}

// ---------------------------------------------------------------------------
// CSR build: histogram -> 3-phase parallel scan -> scatter
// ---------------------------------------------------------------------------
__global__ __launch_bounds__(256) void hist_kernel(
    const int* __restrict__ ei, int* __restrict__ counts)
{
    int e = blockIdx.x * 256 + threadIdx.x;
    if (e < N_EDGES) atomicAdd(&counts[ei[N_EDGES + e]], 1);
}

__global__ __launch_bounds__(256) void scan_phase_a(
    const int* __restrict__ counts,
    int* __restrict__ row_ptr, int* __restrict__ block_sums)
{
    __shared__ int lds[256];
    int t = threadIdx.x;
    int i = blockIdx.x * 256 + t;
    int v = (i < N_NODES) ? counts[i] : 0;
    lds[t] = v;
    __syncthreads();
    for (int off = 1; off < 256; off <<= 1) {
        int u = (t >= off) ? lds[t - off] : 0;
        __syncthreads();
        lds[t] += u;
        __syncthreads();
    }
    if (i < N_NODES) row_ptr[i] = lds[t] - v;
    if (t == 255) block_sums[blockIdx.x] = lds[255];
}

__global__ __launch_bounds__(1024) void scan_phase_b(
    int* __restrict__ block_sums)
{
    __shared__ int lds[1024];
    int t = threadIdx.x;
    int v = (t < SCAN_BLOCKS) ? block_sums[t] : 0;
    lds[t] = v;
    __syncthreads();
    for (int off = 1; off < 1024; off <<= 1) {
        int u = (t >= off) ? lds[t - off] : 0;
        __syncthreads();
        lds[t] += u;
        __syncthreads();
    }
    if (t < SCAN_BLOCKS) block_sums[t] = lds[t] - v;
}

__global__ __launch_bounds__(256) void scan_phase_c(
    const int* __restrict__ block_sums,
    int* __restrict__ row_ptr, int* __restrict__ cursor)
{
    int i = blockIdx.x * 256 + threadIdx.x;
    if (i < N_NODES) {
        int v = row_ptr[i] + block_sums[blockIdx.x];
        row_ptr[i] = v;
        cursor[i] = v;
    }
    if (i == 0) row_ptr[N_NODES] = N_EDGES;
}

__global__ __launch_bounds__(256) void scatter_kernel(
    const int* __restrict__ ei, int* __restrict__ cursor,
    int* __restrict__ src_sorted, int* __restrict__ eid_sorted)
{
    int e = blockIdx.x * 256 + threadIdx.x;
    if (e >= N_EDGES) return;
    int d = ei[N_EDGES + e];
    int pos = atomicAdd(&cursor[d], 1);
    src_sorted[pos] = ei[e];
    eid_sorted[pos] = e;
}

// ---------------------------------------------------------------------------
// Edge-message via MFMA (validated R16).
// ---------------------------------------------------------------------------
#define EMSG_WAVES 8192
template<int DIN>
__global__ __launch_bounds__(256) void emsg_mfma(
    const float* __restrict__ ea,
    const int*   __restrict__ eid_sorted,
    const float* __restrict__ We,     // [DIN, 16]
    const float* __restrict__ be,     // [DIN]
    unsigned short* __restrict__ emsg)  // [E, DIN] bf16, sorted order
{
    constexpr int NFT = (DIN + 15) / 16;
    int lane = threadIdx.x & 63;
    int wv = blockIdx.x * 4 + (threadIdx.x >> 6);
    int r = lane & 15, g = lane >> 4;
    const short8 zero8 = (short8){0, 0, 0, 0, 0, 0, 0, 0};

    short8 af[NFT];
    float4 bb[NFT];
    bool   sv[NFT];
#pragma unroll
    for (int ft = 0; ft < NFT; ft++) {
        int feat = ft * 16 + r;
        if (g < 2 && feat < DIN) {
            const float4* w4 = (const float4*)(We + feat * 16 + g * 8);
            af[ft] = cvt8(w4[0], w4[1]);
        } else {
            af[ft] = zero8;
        }
        int feat0 = ft * 16 + g * 4;
        sv[ft] = (feat0 < DIN);
        bb[ft] = sv[ft] ? *(const float4*)(be + feat0)
                        : make_float4(0.f, 0.f, 0.f, 0.f);
    }

    const int NT = N_EDGES / 16;
#pragma unroll 1
    for (int tile = wv; tile < NT; tile += EMSG_WAVES) {
        int j0 = tile * 16;
        int e = eid_sorted[j0 + r];
        short8 zf = zero8;
        if (g < 2) {
            const float4* ep = (const float4*)(ea + (size_t)e * 16 + g * 8);
            zf = cvt8(ep[0], ep[1]);
        }
#pragma unroll
        for (int ft = 0; ft < NFT; ft++) {
            f32x4 acc = (f32x4){0.f, 0.f, 0.f, 0.f};
            acc = __builtin_amdgcn_mfma_f32_16x16x32_bf16(af[ft], zf, acc, 0, 0, 0);
            if (sv[ft]) {
                ushort4 st;
                st.x = f2bf(acc[0] + bb[ft].x);
                st.y = f2bf(acc[1] + bb[ft].y);
                st.z = f2bf(acc[2] + bb[ft].z);
                st.w = f2bf(acc[3] + bb[ft].w);
                *(ushort4*)(emsg + (size_t)(j0 + r) * DIN + ft * 16 + g * 4) = st;
            }
        }
    }
}

// ---------------------------------------------------------------------------
// Gather-aggregate v4 (validated R15/R16).
// ---------------------------------------------------------------------------
template<int DIN>
__global__ __launch_bounds__(256) void agg_pre(
    const unsigned short* __restrict__ feat,  // [N, DIN] bf16
    const int*   __restrict__ row_ptr,
    const int*   __restrict__ src_sorted,
    const unsigned short* __restrict__ emsg,  // [E, DIN] bf16 sorted
    unsigned short* __restrict__ AGGb)        // [N, 64] bf16 (x_dst + agg)
{
    int lane = threadIdx.x & 63;
    int wv = blockIdx.x * 4 + (threadIdx.x >> 6);
    int n0 = wv * 8;
    if (n0 >= N_NODES) return;
    int eg = lane >> 4;
    int f4 = lane & 15;
    const bool vf = (f4 * 4 < DIN);
    const int f4c = vf ? f4 : 0;

    int lo = row_ptr[n0];
#pragma unroll 1
    for (int ni = 0; ni < 8; ni++) {
        int node = n0 + ni;
        int hi = row_ptr[node + 1];
        float4 acc = {0.f, 0.f, 0.f, 0.f};
#pragma unroll 1
        for (int j0 = lo; j0 < hi; j0 += 4) {
            int j = j0 + eg;
            bool ev = (j < hi);
            int jc = ev ? j : (hi - 1);
            int s = src_sorted[jc];
            ushort4 xu = *(const ushort4*)(feat + (size_t)s * DIN + f4c * 4);
            ushort4 mu = *(const ushort4*)(emsg + (size_t)jc * DIN + f4c * 4);
            float4 xv = bf4f(xu), mv = bf4f(mu);
            float t0 = fmaxf(xv.x + mv.x, 0.f);
            float t1 = fmaxf(xv.y + mv.y, 0.f);
            float t2 = fmaxf(xv.z + mv.z, 0.f);
            float t3 = fmaxf(xv.w + mv.w, 0.f);
            if (ev && vf) {
                acc.x += t0; acc.y += t1; acc.z += t2; acc.w += t3;
            }
        }
        acc.x += __shfl_xor(acc.x, 16, 64);
        acc.y += __shfl_xor(acc.y, 16, 64);
        acc.z += __shfl_xor(acc.z, 16, 64);
        acc.w += __shfl_xor(acc.w, 16, 64);
        acc.x += __shfl_xor(acc.x, 32, 64);
        acc.y += __shfl_xor(acc.y, 32, 64);
        acc.z += __shfl_xor(acc.z, 32, 64);
        acc.w += __shfl_xor(acc.w, 32, 64);
        if (eg == 0) {
            float4 xd = {0.f, 0.f, 0.f, 0.f};
            if (vf) xd = bf4f(*(const ushort4*)(feat + (size_t)node * DIN + f4 * 4));
            float4 o = vf ? make_float4(acc.x + xd.x, acc.y + xd.y,
                                        acc.z + xd.z, acc.w + xd.w)
                          : make_float4(0.f, 0.f, 0.f, 0.f);
            ushort4 st;
            st.x = f2bf(o.x); st.y = f2bf(o.y);
            st.z = f2bf(o.z); st.w = f2bf(o.w);
            *(ushort4*)(AGGb + (size_t)node * HDIM + f4 * 4) = st;
        }
        lo = hi;
    }
}

// ---------------------------------------------------------------------------
// Gather-aggregate fallback (no emsg workspace): fused edge MLP via SGPRs.
// ---------------------------------------------------------------------------
template<int DIN>
__global__ __launch_bounds__(256) void agg_kernel(
    const unsigned short* __restrict__ feat,
    const int*   __restrict__ row_ptr,
    const int*   __restrict__ src_sorted,
    const int*   __restrict__ eid_sorted,
    const float* __restrict__ ea,
    const float* __restrict__ We,
    const float* __restrict__ be,
    unsigned short* __restrict__ AGGb)
{
    int lane = threadIdx.x & 63;
    int wv = __builtin_amdgcn_readfirstlane(blockIdx.x * 4 + (threadIdx.x >> 6));
    int n0 = wv * 8;
    if (n0 >= N_NODES) return;
    int f = lane;

    float wrow[16];
    float bias = 0.f;
    if (f < DIN) {
#pragma unroll
        for (int j = 0; j < 16; j++) wrow[j] = We[f * 16 + j];
        bias = be[f];
    } else {
#pragma unroll
        for (int j = 0; j < 16; j++) wrow[j] = 0.f;
    }

    int lo = row_ptr[n0];
    int hi = row_ptr[n0 + 8];
    int cur = 0;
    int nb = row_ptr[n0 + 1];
    float acc = 0.f;

    for (int j0 = lo; j0 < hi; j0 += 8) {
        int jn = min(8, hi - j0);
        int s[8], e[8];
#pragma unroll
        for (int k = 0; k < 8; k++) {
            int j = min(j0 + k, hi - 1);
            s[k] = src_sorted[j];
            e[k] = eid_sorted[j];
        }
        float xv[8];
#pragma unroll
        for (int k = 0; k < 8; k++)
            xv[k] = (f < DIN) ? bf2f(feat[(size_t)s[k] * DIN + f]) : 0.f;

#pragma unroll
        for (int k = 0; k < 8; k++) {
            if (k >= jn) break;
            int j = j0 + k;
            while (j >= nb) {
                float xd = (f < DIN) ? bf2f(feat[(size_t)(n0 + cur) * DIN + f]) : 0.f;
                AGGb[(size_t)(n0 + cur) * HDIM + f] = f2bf(acc + xd);
                acc = 0.f;
                cur++;
                nb = row_ptr[n0 + cur + 1];
            }
            const float4* ep = (const float4*)(ea + (size_t)e[k] * 16);
            float4 q0 = ep[0], q1 = ep[1], q2 = ep[2], q3 = ep[3];
            float a = bias;
            a = fmaf(q0.x, wrow[0],  a); a = fmaf(q0.y, wrow[1],  a);
            a = fmaf(q0.z, wrow[2],  a); a = fmaf(q0.w, wrow[3],  a);
            a = fmaf(q1.x, wrow[4],  a); a = fmaf(q1.y, wrow[5],  a);
            a = fmaf(q1.z, wrow[6],  a); a = fmaf(q1.w, wrow[7],  a);
            a = fmaf(q2.x, wrow[8],  a); a = fmaf(q2.y, wrow[9],  a);
            a = fmaf(q2.z, wrow[10], a); a = fmaf(q2.w, wrow[11], a);
            a = fmaf(q3.x, wrow[12], a); a = fmaf(q3.y, wrow[13], a);
            a = fmaf(q3.z, wrow[14], a); a = fmaf(q3.w, wrow[15], a);
            acc += fmaxf(xv[k] + a, 0.f);
        }
    }
    while (cur < 8) {
        float xd = (f < DIN) ? bf2f(feat[(size_t)(n0 + cur) * DIN + f]) : 0.f;
        AGGb[(size_t)(n0 + cur) * HDIM + f] = f2bf(acc + xd);
        acc = 0.f;
        cur++;
    }
}

// ---------------------------------------------------------------------------
// Node MFMA: Hb = bf16( leaky_relu(BN(AGGb @ W.T + b)) )
// ---------------------------------------------------------------------------
template<int DIN>
__global__ __launch_bounds__(256) void node_mfma(
    const unsigned short* __restrict__ AGGb,  // [N, 64] bf16
    unsigned short* __restrict__ Hb,          // [N, 64] bf16 out
    const float* __restrict__ W,        // [64, DIN]
    const float* __restrict__ bias,
    const float* __restrict__ gam,
    const float* __restrict__ bet,
    const float* __restrict__ mean,
    const float* __restrict__ var)
{
    int lane = threadIdx.x & 63;
    int wave = blockIdx.x * 4 + (threadIdx.x >> 6);
    if (wave >= N_NODES / 64) return;
    int n0 = wave * 64;
    int r = lane & 15;
    int g = lane >> 4;

    const short8 zero8 = (short8){0, 0, 0, 0, 0, 0, 0, 0};

    short8 zf[4][2];
#pragma unroll
    for (int nt = 0; nt < 4; nt++) {
        int node = n0 + nt * 16 + r;
        const unsigned short* ar = AGGb + (size_t)node * HDIM;
        zf[nt][0] = *(const short8*)(ar + g * 8);
        zf[nt][1] = *(const short8*)(ar + 32 + g * 8);
    }

    const float4* b4  = (const float4*)bias;
    const float4* g4  = (const float4*)gam;
    const float4* be4 = (const float4*)bet;
    const float4* m4  = (const float4*)mean;
    const float4* v4  = (const float4*)var;

#pragma unroll
    for (int ft = 0; ft < 4; ft++) {
        const float* wr = W + (size_t)(ft * 16 + r) * DIN;
        short8 af[2];
        {
            float4 w0 = *(const float4*)(wr + g * 8);
            float4 w1 = *(const float4*)(wr + g * 8 + 4);
            af[0] = cvt8(w0, w1);
            if (DIN == 64) {
                w0 = *(const float4*)(wr + 32 + g * 8);
                w1 = *(const float4*)(wr + 36 + g * 8);
                af[1] = cvt8(w0, w1);
            } else if (g == 0) {
                w0 = *(const float4*)(wr + 32);
                w1 = *(const float4*)(wr + 36);
                af[1] = cvt8(w0, w1);
            } else {
                af[1] = zero8;
            }
        }

        f32x4 acc[4];
#pragma unroll
        for (int nt = 0; nt < 4; nt++) acc[nt] = (f32x4){0.f, 0.f, 0.f, 0.f};

#pragma unroll
        for (int ks = 0; ks < 2; ks++) {
#pragma unroll
            for (int nt = 0; nt < 4; nt++) {
                acc[nt] = __builtin_amdgcn_mfma_f32_16x16x32_bf16(
                    af[ks], zf[nt][ks], acc[nt], 0, 0, 0);
            }
        }

        int idx = ft * 4 + g;
        float4 bb = b4[idx], gg = g4[idx], bt = be4[idx], mm = m4[idx], vv = v4[idx];
        float s0 = gg.x * rsqrtf(vv.x + BN_EPS);
        float s1 = gg.y * rsqrtf(vv.y + BN_EPS);
        float s2 = gg.z * rsqrtf(vv.z + BN_EPS);
        float s3 = gg.w * rsqrtf(vv.w + BN_EPS);
#pragma unroll
        for (int nt = 0; nt < 4; nt++) {
            int node = n0 + nt * 16 + r;
            float y0 = s0 * (acc[nt][0] + bb.x - mm.x) + bt.x;
            float y1 = s1 * (acc[nt][1] + bb.y - mm.y) + bt.y;
            float y2 = s2 * (acc[nt][2] + bb.z - mm.z) + bt.z;
            float y3 = s3 * (acc[nt][3] + bb.w - mm.w) + bt.w;
            y0 = (y0 > 0.f) ? y0 : 0.01f * y0;
            y1 = (y1 > 0.f) ? y1 : 0.01f * y1;
            y2 = (y2 > 0.f) ? y2 : 0.01f * y2;
            y3 = (y3 > 0.f) ? y3 : 0.01f * y3;
            union { uint2 v; unsigned int u[2]; } st;
            st.u[0] = pk2(y0, y1);
            st.u[1] = pk2(y2, y3);
            *(uint2*)(Hb + (size_t)node * HDIM + ft * 16 + g * 4) = st.v;
        }
    }
}

// ---------------------------------------------------------------------------
// Pool: hpool[batch[i]] += h3[i]  (bf16 in, f32 atomic accum; lane = feature
// within node -> per-wave atomics hit one contiguous 256B row: coalesced)
// ---------------------------------------------------------------------------
__global__ __launch_bounds__(256) void pool_kernel(
    const unsigned short* __restrict__ h3b,
    const int*   __restrict__ batch,
    float*       __restrict__ hpool)
{
    int gid = blockIdx.x * 256 + threadIdx.x;
    if (gid >= N_NODES * HDIM) return;
    int i = gid >> 6, f = gid & 63;
    atomicAdd(&hpool[(size_t)batch[i] * HDIM + f], bf2f(h3b[gid]));
}

// ---------------------------------------------------------------------------
// Head v4: NT=4, quarter-LDS staging (32 KB, 4 passes) -> 4 blocks/CU.
// Correctness validated in R17 (absmax 0.125); perf isolated this round.
// ---------------------------------------------------------------------------
__global__ __launch_bounds__(256, 4) void head_kernel(
    const unsigned short* __restrict__ h1b,
    const unsigned short* __restrict__ h2b,
    const unsigned short* __restrict__ h3b,
    const float* __restrict__ hpool,
    const int*   __restrict__ batch,
    const float* __restrict__ Wl1, const float* __restrict__ bl1,
    const float* __restrict__ Wl2, const float* __restrict__ bl2,
    float*       __restrict__ out)
{
    __shared__ short8 wlds[2048];    // 32 KB: one quarter (4 ft) of Wl1 fragments

    int tid = threadIdx.x;
    int lane = tid & 63;
    int wave = blockIdx.x * 4 + (tid >> 6);
    bool active = (wave < N_NODES / 64);
    int n0 = active ? wave * 64 : (N_NODES - 64);   // clamp; stores guarded
    int r = lane & 15;
    int g = lane >> 4;

    short8 zf[4][8];
#pragma unroll
    for (int nt = 0; nt < 4; nt++) {
        int node = n0 + nt * 16 + r;
        const unsigned short* r1 = h1b + (size_t)node * 64;
        const unsigned short* r2 = h2b + (size_t)node * 64;
        const unsigned short* r3 = h3b + (size_t)node * 64;
        const float* rp = hpool + (size_t)batch[node] * 64;
        zf[nt][0] = *(const short8*)(r1 + g * 8);
        zf[nt][1] = *(const short8*)(r1 + 32 + g * 8);
        zf[nt][2] = *(const short8*)(r2 + g * 8);
        zf[nt][3] = *(const short8*)(r2 + 32 + g * 8);
        zf[nt][4] = *(const short8*)(r3 + g * 8);
        zf[nt][5] = *(const short8*)(r3 + 32 + g * 8);
        const float4* q;
        q = (const float4*)(rp + g * 8);        zf[nt][6] = cvt8(q[0], q[1]);
        q = (const float4*)(rp + 32 + g * 8);   zf[nt][7] = cvt8(q[0], q[1]);
    }

    float p[4] = {0.f, 0.f, 0.f, 0.f};
    const float4* bl1_4 = (const float4*)bl1;
    const float4* wl2_4 = (const float4*)Wl2;

#pragma unroll 1
    for (int pass = 0; pass < 4; pass++) {
        if (pass) __syncthreads();           // drain previous pass before restage
        // ---- stage 2048 fragments (ft = pass*4 .. pass*4+3) ----
#pragma unroll
        for (int i = 0; i < 8; i++) {
            int local = tid + i * 256;       // 0..2047
            int ftq = local >> 9;            // 0..3
            int ks  = (local >> 6) & 7;
            int lf  = local & 63;
            int rr = lf & 15, gg = lf >> 4;
            int ft = pass * 4 + ftq;
            const float4* q = (const float4*)(Wl1 + (size_t)(ft * 16 + rr) * 256
                                              + ks * 32 + gg * 8);
            wlds[local] = cvt8(q[0], q[1]);
        }
        __syncthreads();

        // ---- compute 4 ft with LDS A-fragments ----
#pragma unroll 1
        for (int ftq = 0; ftq < 4; ftq++) {
            int ft = pass * 4 + ftq;
            short8 af[8];
#pragma unroll
            for (int ks = 0; ks < 8; ks++) af[ks] = wlds[(ftq * 8 + ks) * 64 + lane];

            f32x4 acc[4];
#pragma unroll
            for (int nt = 0; nt < 4; nt++) acc[nt] = (f32x4){0.f, 0.f, 0.f, 0.f};
#pragma unroll
            for (int ks = 0; ks < 8; ks++) {
#pragma unroll
                for (int nt = 0; nt < 4; nt++) {
                    acc[nt] = __builtin_amdgcn_mfma_f32_16x16x32_bf16(
                        af[ks], zf[nt][ks], acc[nt], 0, 0, 0);
                }
            }

            float4 bl = bl1_4[ft * 4 + g];
            float4 w2 = wl2_4[ft * 4 + g];
#pragma unroll
            for (int nt = 0; nt < 4; nt++) {
                float a0 = acc[nt][0] + bl.x;
                float a1 = acc[nt][1] + bl.y;
                float a2 = acc[nt][2] + bl.z;
                float a3 = acc[nt][3] + bl.w;
                a0 = (a0 > 0.f) ? a0 : 0.01f * a0;
                a1 = (a1 > 0.f) ? a1 : 0.01f * a1;
                a2 = (a2 > 0.f) ? a2 : 0.01f * a2;
                a3 = (a3 > 0.f) ? a3 : 0.01f * a3;
                p[nt] += w2.x * a0 + w2.y * a1 + w2.z * a2 + w2.w * a3;
            }
        }
    }

    float b2 = bl2[0];
#pragma unroll
    for (int nt = 0; nt < 4; nt++) {
        float s = p[nt];
        s += __shfl_xor(s, 16, 64);
        s += __shfl_xor(s, 32, 64);
        if (g == 0 && active) out[n0 + nt * 16 + r] = s + b2;
    }
}

// ---------------------------------------------------------------------------
extern "C" void kernel_launch(void* const* d_in, const int* in_sizes, int n_in,
                              void* d_out, int out_size, void* d_ws, size_t ws_size,
                              hipStream_t stream) {
    const float* x     = (const float*)d_in[0];
    const int*   ei    = (const int*)  d_in[1];
    const float* ea    = (const float*)d_in[2];
    const int*   batch = (const int*)  d_in[3];

    const float* We1 = (const float*)d_in[4];  const float* be1 = (const float*)d_in[5];
    const float* W1  = (const float*)d_in[6];  const float* b1  = (const float*)d_in[7];
    const float* g1  = (const float*)d_in[8];  const float* bb1 = (const float*)d_in[9];
    const float* m1  = (const float*)d_in[10]; const float* v1  = (const float*)d_in[11];

    const float* We2 = (const float*)d_in[12]; const float* be2 = (const float*)d_in[13];
    const float* W2  = (const float*)d_in[14]; const float* b2  = (const float*)d_in[15];
    const float* g2  = (const float*)d_in[16]; const float* bb2 = (const float*)d_in[17];
    const float* m2  = (const float*)d_in[18]; const float* v2  = (const float*)d_in[19];

    const float* We3 = (const float*)d_in[20]; const float* be3 = (const float*)d_in[21];
    const float* W3  = (const float*)d_in[22]; const float* b3  = (const float*)d_in[23];
    const float* g3  = (const float*)d_in[24]; const float* bb3 = (const float*)d_in[25];
    const float* m3  = (const float*)d_in[26]; const float* v3  = (const float*)d_in[27];

    const float* Wl1 = (const float*)d_in[28]; const float* bl1 = (const float*)d_in[29];
    const float* Wl2 = (const float*)d_in[30]; const float* bl2 = (const float*)d_in[31];

    float* out = (float*)d_out;

    // ---- workspace carve-out, every buffer 256B-aligned ----
    char* wp = (char*)d_ws;
    auto carve = [&](size_t bytes) -> char* {
        char* r = wp;
        wp += (bytes + 255) & ~(size_t)255;
        return r;
    };
    unsigned short* AGGb  = (unsigned short*)carve((size_t)N_NODES * HDIM * 2);
    unsigned short* xb    = (unsigned short*)carve((size_t)N_NODES * 40 * 2);
    unsigned short* Hb1   = (unsigned short*)carve((size_t)N_NODES * HDIM * 2);
    unsigned short* Hb2   = (unsigned short*)carve((size_t)N_NODES * HDIM * 2);
    unsigned short* Hb3   = (unsigned short*)carve((size_t)N_NODES * HDIM * 2);
    float* hpool          = (float*)         carve((size_t)N_MOL * HDIM * 4);
    int* counts           = (int*)           carve((size_t)N_NODES * 4);
    int* row_ptr          = (int*)           carve((size_t)(N_NODES + 1) * 4);
    int* cursor           = (int*)           carve((size_t)N_NODES * 4);
    int* src_sorted       = (int*)           carve((size_t)N_EDGES * 4);
    int* eid_sorted       = (int*)           carve((size_t)N_EDGES * 4);
    int* block_sums       = (int*)           carve((size_t)SCAN_BLOCKS * 4);
    unsigned short* emsg  = (unsigned short*)carve((size_t)N_EDGES * HDIM * 2);
    size_t need           = (size_t)(wp - (char*)d_ws);
    bool use_pre = (ws_size >= need);

    hipMemsetAsync(hpool, 0, (size_t)N_MOL * HDIM * sizeof(float), stream);
    hipMemsetAsync(counts, 0, (size_t)N_NODES * sizeof(int), stream);

    dim3 blk(256);
    dim3 cgrid(((size_t)N_NODES * 40 / 4 + 255) / 256);
    dim3 egrid(N_EDGES / 256);
    dim3 mgrid(EMSG_WAVES / 4);
    dim3 sgrid(SCAN_BLOCKS);
    dim3 agrid((N_NODES / 8) / 4);
    dim3 ngrid((N_NODES / 64 + 3) / 4);
    dim3 pgrid((N_NODES * HDIM) / 256);
    dim3 hgrid((N_NODES / 64 + 3) / 4);

    // ---- prep ----
    cvtx_kernel<<<cgrid, blk, 0, stream>>>(x, xb);
    hist_kernel<<<egrid, blk, 0, stream>>>(ei, counts);
    scan_phase_a<<<sgrid, blk, 0, stream>>>(counts, row_ptr, block_sums);
    scan_phase_b<<<1, 1024, 0, stream>>>(block_sums);
    scan_phase_c<<<sgrid, blk, 0, stream>>>(block_sums, row_ptr, cursor);
    scatter_kernel<<<egrid, blk, 0, stream>>>(ei, cursor, src_sorted, eid_sorted);

    if (use_pre) {
        emsg_mfma<40><<<mgrid, blk, 0, stream>>>(ea, eid_sorted, We1, be1, emsg);
        agg_pre<40><<<agrid, blk, 0, stream>>>(xb, row_ptr, src_sorted, emsg, AGGb);
        node_mfma<40><<<ngrid, blk, 0, stream>>>(AGGb, Hb1, W1, b1, g1, bb1, m1, v1);
        emsg_mfma<64><<<mgrid, blk, 0, stream>>>(ea, eid_sorted, We2, be2, emsg);
        agg_pre<64><<<agrid, blk, 0, stream>>>(Hb1, row_ptr, src_sorted, emsg, AGGb);
        node_mfma<64><<<ngrid, blk, 0, stream>>>(AGGb, Hb2, W2, b2, g2, bb2, m2, v2);
        emsg_mfma<64><<<mgrid, blk, 0, stream>>>(ea, eid_sorted, We3, be3, emsg);
        agg_pre<64><<<agrid, blk, 0, stream>>>(Hb2, row_ptr, src_sorted, emsg, AGGb);
        node_mfma<64><<<ngrid, blk, 0, stream>>>(AGGb, Hb3, W3, b3, g3, bb3, m3, v3);
    } else {
        agg_kernel<40><<<agrid, blk, 0, stream>>>(xb, row_ptr, src_sorted, eid_sorted,
                                                  ea, We1, be1, AGGb);
        node_mfma<40><<<ngrid, blk, 0, stream>>>(AGGb, Hb1, W1, b1, g1, bb1, m1, v1);
        agg_kernel<64><<<agrid, blk, 0, stream>>>(Hb1, row_ptr, src_sorted, eid_sorted,
                                                  ea, We2, be2, AGGb);
        node_mfma<64><<<ngrid, blk, 0, stream>>>(AGGb, Hb2, W2, b2, g2, bb2, m2, v2);
        agg_kernel<64><<<agrid, blk, 0, stream>>>(Hb2, row_ptr, src_sorted, eid_sorted,
                                                  ea, We3, be3, AGGb);
        node_mfma<64><<<ngrid, blk, 0, stream>>>(AGGb, Hb3, W3, b3, g3, bb3, m3, v3);
    }

    // pool
    pool_kernel<<<pgrid, blk, 0, stream>>>(Hb3, batch, hpool);
    // head
    head_kernel<<<hgrid, blk, 0, stream>>>(Hb1, Hb2, Hb3, hpool, batch,
                                           Wl1, bl1, Wl2, bl2, out);
}

// Round 20
// 580.531 us; speedup vs baseline: 1.1078x; 1.1078x over previous
//
#include <hip/hip_runtime.h>
#include <hip/hip_bf16.h>

#define N_NODES 200000
#define N_EDGES 800000
#define N_MOL   10000
#define HDIM    64
#define EDGE_DIM 16
#define BN_EPS 1e-5f
#define SCAN_BLOCKS ((N_NODES + 255) / 256)   // 782

typedef __attribute__((ext_vector_type(8))) short short8;
typedef __attribute__((ext_vector_type(4))) float f32x4;

// ---------------------------------------------------------------------------
// bf16 helpers
// ---------------------------------------------------------------------------
__device__ __forceinline__ unsigned int pk2(float a, float b) {
    __hip_bfloat162 h = __float22bfloat162_rn(make_float2(a, b));
    union { __hip_bfloat162 h; unsigned int u; } c;
    c.h = h;
    return c.u;
}
__device__ __forceinline__ short8 cvt8(float4 a, float4 b) {
    union { short8 s; unsigned int u[4]; } r;
    r.u[0] = pk2(a.x, a.y); r.u[1] = pk2(a.z, a.w);
    r.u[2] = pk2(b.x, b.y); r.u[3] = pk2(b.z, b.w);
    return r.s;
}
__device__ __forceinline__ float bf2f(unsigned short u) {
    return __uint_as_float(((unsigned int)u) << 16);
}
__device__ __forceinline__ unsigned short f2bf(float a) {
    union { __hip_bfloat16 h; unsigned short u; } c;
    c.h = __float2bfloat16(a);
    return c.u;
}
__device__ __forceinline__ float4 bf4f(ushort4 u) {
    return make_float4(bf2f(u.x), bf2f(u.y), bf2f(u.z), bf2f(u.w));
}

// ---------------------------------------------------------------------------
// x -> bf16 copy (layer-1 gather source)
// ---------------------------------------------------------------------------
__global__ __launch_bounds__(256) void cvtx_kernel(
    const float* __restrict__ x, unsigned short* __restrict__ xb)
{
    int i = blockIdx.x * 256 + threadIdx.x;
    if ((size_t)i * 4 >= (size_t)N_NODES * 40) return;
    float4 v = *(const float4*)(x + (size_t)i * 4);
    union { ushort4 s; unsigned int u[2]; } r;
    r.u[0] = pk2(v.x, v.y); r.u[1] = pk2(v.z, v.w);
    *(ushort4*)(xb + (size_t)i * 4) = r.s;
}

// ---------------------------------------------------------------------------
// CSR build: histogram -> 3-phase parallel scan -> scatter
// ---------------------------------------------------------------------------
__global__ __launch_bounds__(256) void hist_kernel(
    const int* __restrict__ ei, int* __restrict__ counts)
{
    int e = blockIdx.x * 256 + threadIdx.x;
    if (e < N_EDGES) atomicAdd(&counts[ei[N_EDGES + e]], 1);
}

__global__ __launch_bounds__(256) void scan_phase_a(
    const int* __restrict__ counts,
    int* __restrict__ row_ptr, int* __restrict__ block_sums)
{
    __shared__ int lds[256];
    int t = threadIdx.x;
    int i = blockIdx.x * 256 + t;
    int v = (i < N_NODES) ? counts[i] : 0;
    lds[t] = v;
    __syncthreads();
    for (int off = 1; off < 256; off <<= 1) {
        int u = (t >= off) ? lds[t - off] : 0;
        __syncthreads();
        lds[t] += u;
        __syncthreads();
    }
    if (i < N_NODES) row_ptr[i] = lds[t] - v;
    if (t == 255) block_sums[blockIdx.x] = lds[255];
}

__global__ __launch_bounds__(1024) void scan_phase_b(
    int* __restrict__ block_sums)
{
    __shared__ int lds[1024];
    int t = threadIdx.x;
    int v = (t < SCAN_BLOCKS) ? block_sums[t] : 0;
    lds[t] = v;
    __syncthreads();
    for (int off = 1; off < 1024; off <<= 1) {
        int u = (t >= off) ? lds[t - off] : 0;
        __syncthreads();
        lds[t] += u;
        __syncthreads();
    }
    if (t < SCAN_BLOCKS) block_sums[t] = lds[t] - v;
}

__global__ __launch_bounds__(256) void scan_phase_c(
    const int* __restrict__ block_sums,
    int* __restrict__ row_ptr, int* __restrict__ cursor)
{
    int i = blockIdx.x * 256 + threadIdx.x;
    if (i < N_NODES) {
        int v = row_ptr[i] + block_sums[blockIdx.x];
        row_ptr[i] = v;
        cursor[i] = v;
    }
    if (i == 0) row_ptr[N_NODES] = N_EDGES;
}

__global__ __launch_bounds__(256) void scatter_kernel(
    const int* __restrict__ ei, int* __restrict__ cursor,
    int* __restrict__ src_sorted, int* __restrict__ eid_sorted)
{
    int e = blockIdx.x * 256 + threadIdx.x;
    if (e >= N_EDGES) return;
    int d = ei[N_EDGES + e];
    int pos = atomicAdd(&cursor[d], 1);
    src_sorted[pos] = ei[e];
    eid_sorted[pos] = e;
}

// ---------------------------------------------------------------------------
// Edge-message via MFMA (validated R16).
// ---------------------------------------------------------------------------
#define EMSG_WAVES 8192
template<int DIN>
__global__ __launch_bounds__(256) void emsg_mfma(
    const float* __restrict__ ea,
    const int*   __restrict__ eid_sorted,
    const float* __restrict__ We,     // [DIN, 16]
    const float* __restrict__ be,     // [DIN]
    unsigned short* __restrict__ emsg)  // [E, DIN] bf16, sorted order
{
    constexpr int NFT = (DIN + 15) / 16;
    int lane = threadIdx.x & 63;
    int wv = blockIdx.x * 4 + (threadIdx.x >> 6);
    int r = lane & 15, g = lane >> 4;
    const short8 zero8 = (short8){0, 0, 0, 0, 0, 0, 0, 0};

    short8 af[NFT];
    float4 bb[NFT];
    bool   sv[NFT];
#pragma unroll
    for (int ft = 0; ft < NFT; ft++) {
        int feat = ft * 16 + r;
        if (g < 2 && feat < DIN) {
            const float4* w4 = (const float4*)(We + feat * 16 + g * 8);
            af[ft] = cvt8(w4[0], w4[1]);
        } else {
            af[ft] = zero8;
        }
        int feat0 = ft * 16 + g * 4;
        sv[ft] = (feat0 < DIN);
        bb[ft] = sv[ft] ? *(const float4*)(be + feat0)
                        : make_float4(0.f, 0.f, 0.f, 0.f);
    }

    const int NT = N_EDGES / 16;
#pragma unroll 1
    for (int tile = wv; tile < NT; tile += EMSG_WAVES) {
        int j0 = tile * 16;
        int e = eid_sorted[j0 + r];
        short8 zf = zero8;
        if (g < 2) {
            const float4* ep = (const float4*)(ea + (size_t)e * 16 + g * 8);
            zf = cvt8(ep[0], ep[1]);
        }
#pragma unroll
        for (int ft = 0; ft < NFT; ft++) {
            f32x4 acc = (f32x4){0.f, 0.f, 0.f, 0.f};
            acc = __builtin_amdgcn_mfma_f32_16x16x32_bf16(af[ft], zf, acc, 0, 0, 0);
            if (sv[ft]) {
                ushort4 st;
                st.x = f2bf(acc[0] + bb[ft].x);
                st.y = f2bf(acc[1] + bb[ft].y);
                st.z = f2bf(acc[2] + bb[ft].z);
                st.w = f2bf(acc[3] + bb[ft].w);
                *(ushort4*)(emsg + (size_t)(j0 + r) * DIN + ft * 16 + g * 4) = st;
            }
        }
    }
}

// ---------------------------------------------------------------------------
// Gather-aggregate v4 (validated R15/R16).
// ---------------------------------------------------------------------------
template<int DIN>
__global__ __launch_bounds__(256) void agg_pre(
    const unsigned short* __restrict__ feat,  // [N, DIN] bf16
    const int*   __restrict__ row_ptr,
    const int*   __restrict__ src_sorted,
    const unsigned short* __restrict__ emsg,  // [E, DIN] bf16 sorted
    unsigned short* __restrict__ AGGb)        // [N, 64] bf16 (x_dst + agg)
{
    int lane = threadIdx.x & 63;
    int wv = blockIdx.x * 4 + (threadIdx.x >> 6);
    int n0 = wv * 8;
    if (n0 >= N_NODES) return;
    int eg = lane >> 4;
    int f4 = lane & 15;
    const bool vf = (f4 * 4 < DIN);
    const int f4c = vf ? f4 : 0;

    int lo = row_ptr[n0];
#pragma unroll 1
    for (int ni = 0; ni < 8; ni++) {
        int node = n0 + ni;
        int hi = row_ptr[node + 1];
        float4 acc = {0.f, 0.f, 0.f, 0.f};
#pragma unroll 1
        for (int j0 = lo; j0 < hi; j0 += 4) {
            int j = j0 + eg;
            bool ev = (j < hi);
            int jc = ev ? j : (hi - 1);
            int s = src_sorted[jc];
            ushort4 xu = *(const ushort4*)(feat + (size_t)s * DIN + f4c * 4);
            ushort4 mu = *(const ushort4*)(emsg + (size_t)jc * DIN + f4c * 4);
            float4 xv = bf4f(xu), mv = bf4f(mu);
            float t0 = fmaxf(xv.x + mv.x, 0.f);
            float t1 = fmaxf(xv.y + mv.y, 0.f);
            float t2 = fmaxf(xv.z + mv.z, 0.f);
            float t3 = fmaxf(xv.w + mv.w, 0.f);
            if (ev && vf) {
                acc.x += t0; acc.y += t1; acc.z += t2; acc.w += t3;
            }
        }
        acc.x += __shfl_xor(acc.x, 16, 64);
        acc.y += __shfl_xor(acc.y, 16, 64);
        acc.z += __shfl_xor(acc.z, 16, 64);
        acc.w += __shfl_xor(acc.w, 16, 64);
        acc.x += __shfl_xor(acc.x, 32, 64);
        acc.y += __shfl_xor(acc.y, 32, 64);
        acc.z += __shfl_xor(acc.z, 32, 64);
        acc.w += __shfl_xor(acc.w, 32, 64);
        if (eg == 0) {
            float4 xd = {0.f, 0.f, 0.f, 0.f};
            if (vf) xd = bf4f(*(const ushort4*)(feat + (size_t)node * DIN + f4 * 4));
            float4 o = vf ? make_float4(acc.x + xd.x, acc.y + xd.y,
                                        acc.z + xd.z, acc.w + xd.w)
                          : make_float4(0.f, 0.f, 0.f, 0.f);
            ushort4 st;
            st.x = f2bf(o.x); st.y = f2bf(o.y);
            st.z = f2bf(o.z); st.w = f2bf(o.w);
            *(ushort4*)(AGGb + (size_t)node * HDIM + f4 * 4) = st;
        }
        lo = hi;
    }
}

// ---------------------------------------------------------------------------
// Gather-aggregate fallback (no emsg workspace): fused edge MLP via SGPRs.
// ---------------------------------------------------------------------------
template<int DIN>
__global__ __launch_bounds__(256) void agg_kernel(
    const unsigned short* __restrict__ feat,
    const int*   __restrict__ row_ptr,
    const int*   __restrict__ src_sorted,
    const int*   __restrict__ eid_sorted,
    const float* __restrict__ ea,
    const float* __restrict__ We,
    const float* __restrict__ be,
    unsigned short* __restrict__ AGGb)
{
    int lane = threadIdx.x & 63;
    int wv = __builtin_amdgcn_readfirstlane(blockIdx.x * 4 + (threadIdx.x >> 6));
    int n0 = wv * 8;
    if (n0 >= N_NODES) return;
    int f = lane;

    float wrow[16];
    float bias = 0.f;
    if (f < DIN) {
#pragma unroll
        for (int j = 0; j < 16; j++) wrow[j] = We[f * 16 + j];
        bias = be[f];
    } else {
#pragma unroll
        for (int j = 0; j < 16; j++) wrow[j] = 0.f;
    }

    int lo = row_ptr[n0];
    int hi = row_ptr[n0 + 8];
    int cur = 0;
    int nb = row_ptr[n0 + 1];
    float acc = 0.f;

    for (int j0 = lo; j0 < hi; j0 += 8) {
        int jn = min(8, hi - j0);
        int s[8], e[8];
#pragma unroll
        for (int k = 0; k < 8; k++) {
            int j = min(j0 + k, hi - 1);
            s[k] = src_sorted[j];
            e[k] = eid_sorted[j];
        }
        float xv[8];
#pragma unroll
        for (int k = 0; k < 8; k++)
            xv[k] = (f < DIN) ? bf2f(feat[(size_t)s[k] * DIN + f]) : 0.f;

#pragma unroll
        for (int k = 0; k < 8; k++) {
            if (k >= jn) break;
            int j = j0 + k;
            while (j >= nb) {
                float xd = (f < DIN) ? bf2f(feat[(size_t)(n0 + cur) * DIN + f]) : 0.f;
                AGGb[(size_t)(n0 + cur) * HDIM + f] = f2bf(acc + xd);
                acc = 0.f;
                cur++;
                nb = row_ptr[n0 + cur + 1];
            }
            const float4* ep = (const float4*)(ea + (size_t)e[k] * 16);
            float4 q0 = ep[0], q1 = ep[1], q2 = ep[2], q3 = ep[3];
            float a = bias;
            a = fmaf(q0.x, wrow[0],  a); a = fmaf(q0.y, wrow[1],  a);
            a = fmaf(q0.z, wrow[2],  a); a = fmaf(q0.w, wrow[3],  a);
            a = fmaf(q1.x, wrow[4],  a); a = fmaf(q1.y, wrow[5],  a);
            a = fmaf(q1.z, wrow[6],  a); a = fmaf(q1.w, wrow[7],  a);
            a = fmaf(q2.x, wrow[8],  a); a = fmaf(q2.y, wrow[9],  a);
            a = fmaf(q2.z, wrow[10], a); a = fmaf(q2.w, wrow[11], a);
            a = fmaf(q3.x, wrow[12], a); a = fmaf(q3.y, wrow[13], a);
            a = fmaf(q3.z, wrow[14], a); a = fmaf(q3.w, wrow[15], a);
            acc += fmaxf(xv[k] + a, 0.f);
        }
    }
    while (cur < 8) {
        float xd = (f < DIN) ? bf2f(feat[(size_t)(n0 + cur) * DIN + f]) : 0.f;
        AGGb[(size_t)(n0 + cur) * HDIM + f] = f2bf(acc + xd);
        acc = 0.f;
        cur++;
    }
}

// ---------------------------------------------------------------------------
// Node MFMA: Hb = bf16( leaky_relu(BN(AGGb @ W.T + b)) )
// ---------------------------------------------------------------------------
template<int DIN>
__global__ __launch_bounds__(256) void node_mfma(
    const unsigned short* __restrict__ AGGb,  // [N, 64] bf16
    unsigned short* __restrict__ Hb,          // [N, 64] bf16 out
    const float* __restrict__ W,        // [64, DIN]
    const float* __restrict__ bias,
    const float* __restrict__ gam,
    const float* __restrict__ bet,
    const float* __restrict__ mean,
    const float* __restrict__ var)
{
    int lane = threadIdx.x & 63;
    int wave = blockIdx.x * 4 + (threadIdx.x >> 6);
    if (wave >= N_NODES / 64) return;
    int n0 = wave * 64;
    int r = lane & 15;
    int g = lane >> 4;

    const short8 zero8 = (short8){0, 0, 0, 0, 0, 0, 0, 0};

    short8 zf[4][2];
#pragma unroll
    for (int nt = 0; nt < 4; nt++) {
        int node = n0 + nt * 16 + r;
        const unsigned short* ar = AGGb + (size_t)node * HDIM;
        zf[nt][0] = *(const short8*)(ar + g * 8);
        zf[nt][1] = *(const short8*)(ar + 32 + g * 8);
    }

    const float4* b4  = (const float4*)bias;
    const float4* g4  = (const float4*)gam;
    const float4* be4 = (const float4*)bet;
    const float4* m4  = (const float4*)mean;
    const float4* v4  = (const float4*)var;

#pragma unroll
    for (int ft = 0; ft < 4; ft++) {
        const float* wr = W + (size_t)(ft * 16 + r) * DIN;
        short8 af[2];
        {
            float4 w0 = *(const float4*)(wr + g * 8);
            float4 w1 = *(const float4*)(wr + g * 8 + 4);
            af[0] = cvt8(w0, w1);
            if (DIN == 64) {
                w0 = *(const float4*)(wr + 32 + g * 8);
                w1 = *(const float4*)(wr + 36 + g * 8);
                af[1] = cvt8(w0, w1);
            } else if (g == 0) {
                w0 = *(const float4*)(wr + 32);
                w1 = *(const float4*)(wr + 36);
                af[1] = cvt8(w0, w1);
            } else {
                af[1] = zero8;
            }
        }

        f32x4 acc[4];
#pragma unroll
        for (int nt = 0; nt < 4; nt++) acc[nt] = (f32x4){0.f, 0.f, 0.f, 0.f};

#pragma unroll
        for (int ks = 0; ks < 2; ks++) {
#pragma unroll
            for (int nt = 0; nt < 4; nt++) {
                acc[nt] = __builtin_amdgcn_mfma_f32_16x16x32_bf16(
                    af[ks], zf[nt][ks], acc[nt], 0, 0, 0);
            }
        }

        int idx = ft * 4 + g;
        float4 bb = b4[idx], gg = g4[idx], bt = be4[idx], mm = m4[idx], vv = v4[idx];
        float s0 = gg.x * rsqrtf(vv.x + BN_EPS);
        float s1 = gg.y * rsqrtf(vv.y + BN_EPS);
        float s2 = gg.z * rsqrtf(vv.z + BN_EPS);
        float s3 = gg.w * rsqrtf(vv.w + BN_EPS);
#pragma unroll
        for (int nt = 0; nt < 4; nt++) {
            int node = n0 + nt * 16 + r;
            float y0 = s0 * (acc[nt][0] + bb.x - mm.x) + bt.x;
            float y1 = s1 * (acc[nt][1] + bb.y - mm.y) + bt.y;
            float y2 = s2 * (acc[nt][2] + bb.z - mm.z) + bt.z;
            float y3 = s3 * (acc[nt][3] + bb.w - mm.w) + bt.w;
            y0 = (y0 > 0.f) ? y0 : 0.01f * y0;
            y1 = (y1 > 0.f) ? y1 : 0.01f * y1;
            y2 = (y2 > 0.f) ? y2 : 0.01f * y2;
            y3 = (y3 > 0.f) ? y3 : 0.01f * y3;
            union { uint2 v; unsigned int u[2]; } st;
            st.u[0] = pk2(y0, y1);
            st.u[1] = pk2(y2, y3);
            *(uint2*)(Hb + (size_t)node * HDIM + ft * 16 + g * 4) = st.v;
        }
    }
}

// ---------------------------------------------------------------------------
// Pool: hpool[batch[i]] += h3[i]  (bf16 in, f32 atomic accum; lane = feature
// within node -> per-wave atomics hit one contiguous 256B row: coalesced)
// ---------------------------------------------------------------------------
__global__ __launch_bounds__(256) void pool_kernel(
    const unsigned short* __restrict__ h3b,
    const int*   __restrict__ batch,
    float*       __restrict__ hpool)
{
    int gid = blockIdx.x * 256 + threadIdx.x;
    if (gid >= N_NODES * HDIM) return;
    int i = gid >> 6, f = gid & 63;
    atomicAdd(&hpool[(size_t)batch[i] * HDIM + f], bf2f(h3b[gid]));
}

// ---------------------------------------------------------------------------
// Head v5: NT=4, quarter-LDS staging (32 KB, 4 passes), launch_bounds(256,2)
// so the allocator keeps ~112 VGPRs (R19's (256,4) forced 64 VGPR -> spills,
// WRITE_SIZE 46 MB). Occupancy becomes LDS-limited: 4 blocks/CU.
// ---------------------------------------------------------------------------
__global__ __launch_bounds__(256, 2) void head_kernel(
    const unsigned short* __restrict__ h1b,
    const unsigned short* __restrict__ h2b,
    const unsigned short* __restrict__ h3b,
    const float* __restrict__ hpool,
    const int*   __restrict__ batch,
    const float* __restrict__ Wl1, const float* __restrict__ bl1,
    const float* __restrict__ Wl2, const float* __restrict__ bl2,
    float*       __restrict__ out)
{
    __shared__ short8 wlds[2048];    // 32 KB: one quarter (4 ft) of Wl1 fragments

    int tid = threadIdx.x;
    int lane = tid & 63;
    int wave = blockIdx.x * 4 + (tid >> 6);
    bool active = (wave < N_NODES / 64);
    int n0 = active ? wave * 64 : (N_NODES - 64);   // clamp; stores guarded
    int r = lane & 15;
    int g = lane >> 4;

    short8 zf[4][8];
#pragma unroll
    for (int nt = 0; nt < 4; nt++) {
        int node = n0 + nt * 16 + r;
        const unsigned short* r1 = h1b + (size_t)node * 64;
        const unsigned short* r2 = h2b + (size_t)node * 64;
        const unsigned short* r3 = h3b + (size_t)node * 64;
        const float* rp = hpool + (size_t)batch[node] * 64;
        zf[nt][0] = *(const short8*)(r1 + g * 8);
        zf[nt][1] = *(const short8*)(r1 + 32 + g * 8);
        zf[nt][2] = *(const short8*)(r2 + g * 8);
        zf[nt][3] = *(const short8*)(r2 + 32 + g * 8);
        zf[nt][4] = *(const short8*)(r3 + g * 8);
        zf[nt][5] = *(const short8*)(r3 + 32 + g * 8);
        const float4* q;
        q = (const float4*)(rp + g * 8);        zf[nt][6] = cvt8(q[0], q[1]);
        q = (const float4*)(rp + 32 + g * 8);   zf[nt][7] = cvt8(q[0], q[1]);
    }

    float p[4] = {0.f, 0.f, 0.f, 0.f};
    const float4* bl1_4 = (const float4*)bl1;
    const float4* wl2_4 = (const float4*)Wl2;

#pragma unroll 1
    for (int pass = 0; pass < 4; pass++) {
        if (pass) __syncthreads();           // drain previous pass before restage
        // ---- stage 2048 fragments (ft = pass*4 .. pass*4+3) ----
#pragma unroll
        for (int i = 0; i < 8; i++) {
            int local = tid + i * 256;       // 0..2047
            int ftq = local >> 9;            // 0..3
            int ks  = (local >> 6) & 7;
            int lf  = local & 63;
            int rr = lf & 15, gg = lf >> 4;
            int ft = pass * 4 + ftq;
            const float4* q = (const float4*)(Wl1 + (size_t)(ft * 16 + rr) * 256
                                              + ks * 32 + gg * 8);
            wlds[local] = cvt8(q[0], q[1]);
        }
        __syncthreads();

        // ---- compute 4 ft with LDS A-fragments ----
#pragma unroll 1
        for (int ftq = 0; ftq < 4; ftq++) {
            int ft = pass * 4 + ftq;
            short8 af[8];
#pragma unroll
            for (int ks = 0; ks < 8; ks++) af[ks] = wlds[(ftq * 8 + ks) * 64 + lane];

            f32x4 acc[4];
#pragma unroll
            for (int nt = 0; nt < 4; nt++) acc[nt] = (f32x4){0.f, 0.f, 0.f, 0.f};
#pragma unroll
            for (int ks = 0; ks < 8; ks++) {
#pragma unroll
                for (int nt = 0; nt < 4; nt++) {
                    acc[nt] = __builtin_amdgcn_mfma_f32_16x16x32_bf16(
                        af[ks], zf[nt][ks], acc[nt], 0, 0, 0);
                }
            }

            float4 bl = bl1_4[ft * 4 + g];
            float4 w2 = wl2_4[ft * 4 + g];
#pragma unroll
            for (int nt = 0; nt < 4; nt++) {
                float a0 = acc[nt][0] + bl.x;
                float a1 = acc[nt][1] + bl.y;
                float a2 = acc[nt][2] + bl.z;
                float a3 = acc[nt][3] + bl.w;
                a0 = (a0 > 0.f) ? a0 : 0.01f * a0;
                a1 = (a1 > 0.f) ? a1 : 0.01f * a1;
                a2 = (a2 > 0.f) ? a2 : 0.01f * a2;
                a3 = (a3 > 0.f) ? a3 : 0.01f * a3;
                p[nt] += w2.x * a0 + w2.y * a1 + w2.z * a2 + w2.w * a3;
            }
        }
    }

    float b2 = bl2[0];
#pragma unroll
    for (int nt = 0; nt < 4; nt++) {
        float s = p[nt];
        s += __shfl_xor(s, 16, 64);
        s += __shfl_xor(s, 32, 64);
        if (g == 0 && active) out[n0 + nt * 16 + r] = s + b2;
    }
}

// ---------------------------------------------------------------------------
extern "C" void kernel_launch(void* const* d_in, const int* in_sizes, int n_in,
                              void* d_out, int out_size, void* d_ws, size_t ws_size,
                              hipStream_t stream) {
    const float* x     = (const float*)d_in[0];
    const int*   ei    = (const int*)  d_in[1];
    const float* ea    = (const float*)d_in[2];
    const int*   batch = (const int*)  d_in[3];

    const float* We1 = (const float*)d_in[4];  const float* be1 = (const float*)d_in[5];
    const float* W1  = (const float*)d_in[6];  const float* b1  = (const float*)d_in[7];
    const float* g1  = (const float*)d_in[8];  const float* bb1 = (const float*)d_in[9];
    const float* m1  = (const float*)d_in[10]; const float* v1  = (const float*)d_in[11];

    const float* We2 = (const float*)d_in[12]; const float* be2 = (const float*)d_in[13];
    const float* W2  = (const float*)d_in[14]; const float* b2  = (const float*)d_in[15];
    const float* g2  = (const float*)d_in[16]; const float* bb2 = (const float*)d_in[17];
    const float* m2  = (const float*)d_in[18]; const float* v2  = (const float*)d_in[19];

    const float* We3 = (const float*)d_in[20]; const float* be3 = (const float*)d_in[21];
    const float* W3  = (const float*)d_in[22]; const float* b3  = (const float*)d_in[23];
    const float* g3  = (const float*)d_in[24]; const float* bb3 = (const float*)d_in[25];
    const float* m3  = (const float*)d_in[26]; const float* v3  = (const float*)d_in[27];

    const float* Wl1 = (const float*)d_in[28]; const float* bl1 = (const float*)d_in[29];
    const float* Wl2 = (const float*)d_in[30]; const float* bl2 = (const float*)d_in[31];

    float* out = (float*)d_out;

    // ---- workspace carve-out, every buffer 256B-aligned ----
    char* wp = (char*)d_ws;
    auto carve = [&](size_t bytes) -> char* {
        char* r = wp;
        wp += (bytes + 255) & ~(size_t)255;
        return r;
    };
    unsigned short* AGGb  = (unsigned short*)carve((size_t)N_NODES * HDIM * 2);
    unsigned short* xb    = (unsigned short*)carve((size_t)N_NODES * 40 * 2);
    unsigned short* Hb1   = (unsigned short*)carve((size_t)N_NODES * HDIM * 2);
    unsigned short* Hb2   = (unsigned short*)carve((size_t)N_NODES * HDIM * 2);
    unsigned short* Hb3   = (unsigned short*)carve((size_t)N_NODES * HDIM * 2);
    float* hpool          = (float*)         carve((size_t)N_MOL * HDIM * 4);
    int* counts           = (int*)           carve((size_t)N_NODES * 4);
    int* row_ptr          = (int*)           carve((size_t)(N_NODES + 1) * 4);
    int* cursor           = (int*)           carve((size_t)N_NODES * 4);
    int* src_sorted       = (int*)           carve((size_t)N_EDGES * 4);
    int* eid_sorted       = (int*)           carve((size_t)N_EDGES * 4);
    int* block_sums       = (int*)           carve((size_t)SCAN_BLOCKS * 4);
    unsigned short* emsg  = (unsigned short*)carve((size_t)N_EDGES * HDIM * 2);
    size_t need           = (size_t)(wp - (char*)d_ws);
    bool use_pre = (ws_size >= need);

    hipMemsetAsync(hpool, 0, (size_t)N_MOL * HDIM * sizeof(float), stream);
    hipMemsetAsync(counts, 0, (size_t)N_NODES * sizeof(int), stream);

    dim3 blk(256);
    dim3 cgrid(((size_t)N_NODES * 40 / 4 + 255) / 256);
    dim3 egrid(N_EDGES / 256);
    dim3 mgrid(EMSG_WAVES / 4);
    dim3 sgrid(SCAN_BLOCKS);
    dim3 agrid((N_NODES / 8) / 4);
    dim3 ngrid((N_NODES / 64 + 3) / 4);
    dim3 pgrid((N_NODES * HDIM) / 256);
    dim3 hgrid((N_NODES / 64 + 3) / 4);

    // ---- prep ----
    cvtx_kernel<<<cgrid, blk, 0, stream>>>(x, xb);
    hist_kernel<<<egrid, blk, 0, stream>>>(ei, counts);
    scan_phase_a<<<sgrid, blk, 0, stream>>>(counts, row_ptr, block_sums);
    scan_phase_b<<<1, 1024, 0, stream>>>(block_sums);
    scan_phase_c<<<sgrid, blk, 0, stream>>>(block_sums, row_ptr, cursor);
    scatter_kernel<<<egrid, blk, 0, stream>>>(ei, cursor, src_sorted, eid_sorted);

    if (use_pre) {
        emsg_mfma<40><<<mgrid, blk, 0, stream>>>(ea, eid_sorted, We1, be1, emsg);
        agg_pre<40><<<agrid, blk, 0, stream>>>(xb, row_ptr, src_sorted, emsg, AGGb);
        node_mfma<40><<<ngrid, blk, 0, stream>>>(AGGb, Hb1, W1, b1, g1, bb1, m1, v1);
        emsg_mfma<64><<<mgrid, blk, 0, stream>>>(ea, eid_sorted, We2, be2, emsg);
        agg_pre<64><<<agrid, blk, 0, stream>>>(Hb1, row_ptr, src_sorted, emsg, AGGb);
        node_mfma<64><<<ngrid, blk, 0, stream>>>(AGGb, Hb2, W2, b2, g2, bb2, m2, v2);
        emsg_mfma<64><<<mgrid, blk, 0, stream>>>(ea, eid_sorted, We3, be3, emsg);
        agg_pre<64><<<agrid, blk, 0, stream>>>(Hb2, row_ptr, src_sorted, emsg, AGGb);
        node_mfma<64><<<ngrid, blk, 0, stream>>>(AGGb, Hb3, W3, b3, g3, bb3, m3, v3);
    } else {
        agg_kernel<40><<<agrid, blk, 0, stream>>>(xb, row_ptr, src_sorted, eid_sorted,
                                                  ea, We1, be1, AGGb);
        node_mfma<40><<<ngrid, blk, 0, stream>>>(AGGb, Hb1, W1, b1, g1, bb1, m1, v1);
        agg_kernel<64><<<agrid, blk, 0, stream>>>(Hb1, row_ptr, src_sorted, eid_sorted,
                                                  ea, We2, be2, AGGb);
        node_mfma<64><<<ngrid, blk, 0, stream>>>(AGGb, Hb2, W2, b2, g2, bb2, m2, v2);
        agg_kernel<64><<<agrid, blk, 0, stream>>>(Hb2, row_ptr, src_sorted, eid_sorted,
                                                  ea, We3, be3, AGGb);
        node_mfma<64><<<ngrid, blk, 0, stream>>>(AGGb, Hb3, W3, b3, g3, bb3, m3, v3);
    }

    // pool
    pool_kernel<<<pgrid, blk, 0, stream>>>(Hb3, batch, hpool);
    // head
    head_kernel<<<hgrid, blk, 0, stream>>>(Hb1, Hb2, Hb3, hpool, batch,
                                           Wl1, bl1, Wl2, bl2, out);
}

// Round 21
// 571.560 us; speedup vs baseline: 1.1252x; 1.0157x over previous
//
#include <hip/hip_runtime.h>
#include <hip/hip_bf16.h>

#define N_NODES 200000
#define N_EDGES 800000
#define N_MOL   10000
#define HDIM    64
#define EDGE_DIM 16
#define BN_EPS 1e-5f
#define SCAN_BLOCKS ((N_NODES + 255) / 256)   // 782

typedef __attribute__((ext_vector_type(8))) short short8;
typedef __attribute__((ext_vector_type(4))) float f32x4;

// ---------------------------------------------------------------------------
// bf16 helpers
// ---------------------------------------------------------------------------
__device__ __forceinline__ unsigned int pk2(float a, float b) {
    __hip_bfloat162 h = __float22bfloat162_rn(make_float2(a, b));
    union { __hip_bfloat162 h; unsigned int u; } c;
    c.h = h;
    return c.u;
}
__device__ __forceinline__ short8 cvt8(float4 a, float4 b) {
    union { short8 s; unsigned int u[4]; } r;
    r.u[0] = pk2(a.x, a.y); r.u[1] = pk2(a.z, a.w);
    r.u[2] = pk2(b.x, b.y); r.u[3] = pk2(b.z, b.w);
    return r.s;
}
__device__ __forceinline__ float bf2f(unsigned short u) {
    return __uint_as_float(((unsigned int)u) << 16);
}
__device__ __forceinline__ unsigned short f2bf(float a) {
    union { __hip_bfloat16 h; unsigned short u; } c;
    c.h = __float2bfloat16(a);
    return c.u;
}
__device__ __forceinline__ float4 bf4f(ushort4 u) {
    return make_float4(bf2f(u.x), bf2f(u.y), bf2f(u.z), bf2f(u.w));
}

// ---------------------------------------------------------------------------
// x -> bf16 copy (layer-1 gather source)
// ---------------------------------------------------------------------------
__global__ __launch_bounds__(256) void cvtx_kernel(
    const float* __restrict__ x, unsigned short* __restrict__ xb)
{
    int i = blockIdx.x * 256 + threadIdx.x;
    if ((size_t)i * 4 >= (size_t)N_NODES * 40) return;
    float4 v = *(const float4*)(x + (size_t)i * 4);
    union { ushort4 s; unsigned int u[2]; } r;
    r.u[0] = pk2(v.x, v.y); r.u[1] = pk2(v.z, v.w);
    *(ushort4*)(xb + (size_t)i * 4) = r.s;
}

// ---------------------------------------------------------------------------
// CSR build: histogram -> 3-phase parallel scan -> scatter
// ---------------------------------------------------------------------------
__global__ __launch_bounds__(256) void hist_kernel(
    const int* __restrict__ ei, int* __restrict__ counts)
{
    int e = blockIdx.x * 256 + threadIdx.x;
    if (e < N_EDGES) atomicAdd(&counts[ei[N_EDGES + e]], 1);
}

__global__ __launch_bounds__(256) void scan_phase_a(
    const int* __restrict__ counts,
    int* __restrict__ row_ptr, int* __restrict__ block_sums)
{
    __shared__ int lds[256];
    int t = threadIdx.x;
    int i = blockIdx.x * 256 + t;
    int v = (i < N_NODES) ? counts[i] : 0;
    lds[t] = v;
    __syncthreads();
    for (int off = 1; off < 256; off <<= 1) {
        int u = (t >= off) ? lds[t - off] : 0;
        __syncthreads();
        lds[t] += u;
        __syncthreads();
    }
    if (i < N_NODES) row_ptr[i] = lds[t] - v;
    if (t == 255) block_sums[blockIdx.x] = lds[255];
}

__global__ __launch_bounds__(1024) void scan_phase_b(
    int* __restrict__ block_sums)
{
    __shared__ int lds[1024];
    int t = threadIdx.x;
    int v = (t < SCAN_BLOCKS) ? block_sums[t] : 0;
    lds[t] = v;
    __syncthreads();
    for (int off = 1; off < 1024; off <<= 1) {
        int u = (t >= off) ? lds[t - off] : 0;
        __syncthreads();
        lds[t] += u;
        __syncthreads();
    }
    if (t < SCAN_BLOCKS) block_sums[t] = lds[t] - v;
}

__global__ __launch_bounds__(256) void scan_phase_c(
    const int* __restrict__ block_sums,
    int* __restrict__ row_ptr, int* __restrict__ cursor)
{
    int i = blockIdx.x * 256 + threadIdx.x;
    if (i < N_NODES) {
        int v = row_ptr[i] + block_sums[blockIdx.x];
        row_ptr[i] = v;
        cursor[i] = v;
    }
    if (i == 0) row_ptr[N_NODES] = N_EDGES;
}

__global__ __launch_bounds__(256) void scatter_kernel(
    const int* __restrict__ ei, int* __restrict__ cursor,
    int* __restrict__ src_sorted, int* __restrict__ eid_sorted)
{
    int e = blockIdx.x * 256 + threadIdx.x;
    if (e >= N_EDGES) return;
    int d = ei[N_EDGES + e];
    int pos = atomicAdd(&cursor[d], 1);
    src_sorted[pos] = ei[e];
    eid_sorted[pos] = e;
}

// ---------------------------------------------------------------------------
// Fused edge-message for ALL 3 layers: gather each edge's ea row ONCE,
// run 11 MFMAs (3 for We1/DIN=40, 4 each for We2/We3), store 3 buffers.
// Fragment conventions identical to validated emsg_mfma (R16).
// ---------------------------------------------------------------------------
#define EMSG_WAVES 8192
__global__ __launch_bounds__(256) void emsg_all(
    const float* __restrict__ ea,
    const int*   __restrict__ eid_sorted,
    const float* __restrict__ We1, const float* __restrict__ be1,
    const float* __restrict__ We2, const float* __restrict__ be2,
    const float* __restrict__ We3, const float* __restrict__ be3,
    unsigned short* __restrict__ em1,   // [E, 40]
    unsigned short* __restrict__ em2,   // [E, 64]
    unsigned short* __restrict__ em3)   // [E, 64]
{
    int lane = threadIdx.x & 63;
    int wv = blockIdx.x * 4 + (threadIdx.x >> 6);
    int r = lane & 15, g = lane >> 4;
    const short8 zero8 = (short8){0, 0, 0, 0, 0, 0, 0, 0};

    // ---- layer-1 fragments (DIN=40, NFT=3) ----
    short8 af1[3]; float4 bb1v[3]; bool sv1[3];
#pragma unroll
    for (int ft = 0; ft < 3; ft++) {
        int feat = ft * 16 + r;
        if (g < 2 && feat < 40) {
            const float4* w4 = (const float4*)(We1 + feat * 16 + g * 8);
            af1[ft] = cvt8(w4[0], w4[1]);
        } else af1[ft] = zero8;
        int feat0 = ft * 16 + g * 4;
        sv1[ft] = (feat0 < 40);
        bb1v[ft] = sv1[ft] ? *(const float4*)(be1 + feat0)
                           : make_float4(0.f, 0.f, 0.f, 0.f);
    }
    // ---- layer-2/3 fragments (DIN=64, NFT=4, all valid) ----
    short8 af2[4], af3[4]; float4 bb2v[4], bb3v[4];
#pragma unroll
    for (int ft = 0; ft < 4; ft++) {
        int feat = ft * 16 + r;
        if (g < 2) {
            const float4* w4 = (const float4*)(We2 + feat * 16 + g * 8);
            af2[ft] = cvt8(w4[0], w4[1]);
            w4 = (const float4*)(We3 + feat * 16 + g * 8);
            af3[ft] = cvt8(w4[0], w4[1]);
        } else { af2[ft] = zero8; af3[ft] = zero8; }
        int feat0 = ft * 16 + g * 4;
        bb2v[ft] = *(const float4*)(be2 + feat0);
        bb3v[ft] = *(const float4*)(be3 + feat0);
    }

    const int NT = N_EDGES / 16;          // 50000 tiles
#pragma unroll 1
    for (int tile = wv; tile < NT; tile += EMSG_WAVES) {
        int j0 = tile * 16;
        int e = eid_sorted[j0 + r];
        short8 zf = zero8;
        if (g < 2) {
            const float4* ep = (const float4*)(ea + (size_t)e * 16 + g * 8);
            zf = cvt8(ep[0], ep[1]);
        }
        // layer 1 (stride 40)
#pragma unroll
        for (int ft = 0; ft < 3; ft++) {
            f32x4 acc = (f32x4){0.f, 0.f, 0.f, 0.f};
            acc = __builtin_amdgcn_mfma_f32_16x16x32_bf16(af1[ft], zf, acc, 0, 0, 0);
            if (sv1[ft]) {
                ushort4 st;
                st.x = f2bf(acc[0] + bb1v[ft].x);
                st.y = f2bf(acc[1] + bb1v[ft].y);
                st.z = f2bf(acc[2] + bb1v[ft].z);
                st.w = f2bf(acc[3] + bb1v[ft].w);
                *(ushort4*)(em1 + (size_t)(j0 + r) * 40 + ft * 16 + g * 4) = st;
            }
        }
        // layer 2 (stride 64)
#pragma unroll
        for (int ft = 0; ft < 4; ft++) {
            f32x4 acc = (f32x4){0.f, 0.f, 0.f, 0.f};
            acc = __builtin_amdgcn_mfma_f32_16x16x32_bf16(af2[ft], zf, acc, 0, 0, 0);
            ushort4 st;
            st.x = f2bf(acc[0] + bb2v[ft].x);
            st.y = f2bf(acc[1] + bb2v[ft].y);
            st.z = f2bf(acc[2] + bb2v[ft].z);
            st.w = f2bf(acc[3] + bb2v[ft].w);
            *(ushort4*)(em2 + (size_t)(j0 + r) * 64 + ft * 16 + g * 4) = st;
        }
        // layer 3 (stride 64)
#pragma unroll
        for (int ft = 0; ft < 4; ft++) {
            f32x4 acc = (f32x4){0.f, 0.f, 0.f, 0.f};
            acc = __builtin_amdgcn_mfma_f32_16x16x32_bf16(af3[ft], zf, acc, 0, 0, 0);
            ushort4 st;
            st.x = f2bf(acc[0] + bb3v[ft].x);
            st.y = f2bf(acc[1] + bb3v[ft].y);
            st.z = f2bf(acc[2] + bb3v[ft].z);
            st.w = f2bf(acc[3] + bb3v[ft].w);
            *(ushort4*)(em3 + (size_t)(j0 + r) * 64 + ft * 16 + g * 4) = st;
        }
    }
}

// ---------------------------------------------------------------------------
// Per-layer edge-message via MFMA (validated R16) — fallback tier.
// ---------------------------------------------------------------------------
template<int DIN>
__global__ __launch_bounds__(256) void emsg_mfma(
    const float* __restrict__ ea,
    const int*   __restrict__ eid_sorted,
    const float* __restrict__ We,     // [DIN, 16]
    const float* __restrict__ be,     // [DIN]
    unsigned short* __restrict__ emsg)  // [E, DIN] bf16, sorted order
{
    constexpr int NFT = (DIN + 15) / 16;
    int lane = threadIdx.x & 63;
    int wv = blockIdx.x * 4 + (threadIdx.x >> 6);
    int r = lane & 15, g = lane >> 4;
    const short8 zero8 = (short8){0, 0, 0, 0, 0, 0, 0, 0};

    short8 af[NFT];
    float4 bb[NFT];
    bool   sv[NFT];
#pragma unroll
    for (int ft = 0; ft < NFT; ft++) {
        int feat = ft * 16 + r;
        if (g < 2 && feat < DIN) {
            const float4* w4 = (const float4*)(We + feat * 16 + g * 8);
            af[ft] = cvt8(w4[0], w4[1]);
        } else {
            af[ft] = zero8;
        }
        int feat0 = ft * 16 + g * 4;
        sv[ft] = (feat0 < DIN);
        bb[ft] = sv[ft] ? *(const float4*)(be + feat0)
                        : make_float4(0.f, 0.f, 0.f, 0.f);
    }

    const int NT = N_EDGES / 16;
#pragma unroll 1
    for (int tile = wv; tile < NT; tile += EMSG_WAVES) {
        int j0 = tile * 16;
        int e = eid_sorted[j0 + r];
        short8 zf = zero8;
        if (g < 2) {
            const float4* ep = (const float4*)(ea + (size_t)e * 16 + g * 8);
            zf = cvt8(ep[0], ep[1]);
        }
#pragma unroll
        for (int ft = 0; ft < NFT; ft++) {
            f32x4 acc = (f32x4){0.f, 0.f, 0.f, 0.f};
            acc = __builtin_amdgcn_mfma_f32_16x16x32_bf16(af[ft], zf, acc, 0, 0, 0);
            if (sv[ft]) {
                ushort4 st;
                st.x = f2bf(acc[0] + bb[ft].x);
                st.y = f2bf(acc[1] + bb[ft].y);
                st.z = f2bf(acc[2] + bb[ft].z);
                st.w = f2bf(acc[3] + bb[ft].w);
                *(ushort4*)(emsg + (size_t)(j0 + r) * DIN + ft * 16 + g * 4) = st;
            }
        }
    }
}

// ---------------------------------------------------------------------------
// Gather-aggregate v4 (validated R15/R16).
// ---------------------------------------------------------------------------
template<int DIN>
__global__ __launch_bounds__(256) void agg_pre(
    const unsigned short* __restrict__ feat,  // [N, DIN] bf16
    const int*   __restrict__ row_ptr,
    const int*   __restrict__ src_sorted,
    const unsigned short* __restrict__ emsg,  // [E, DIN] bf16 sorted
    unsigned short* __restrict__ AGGb)        // [N, 64] bf16 (x_dst + agg)
{
    int lane = threadIdx.x & 63;
    int wv = blockIdx.x * 4 + (threadIdx.x >> 6);
    int n0 = wv * 8;
    if (n0 >= N_NODES) return;
    int eg = lane >> 4;
    int f4 = lane & 15;
    const bool vf = (f4 * 4 < DIN);
    const int f4c = vf ? f4 : 0;

    int lo = row_ptr[n0];
#pragma unroll 1
    for (int ni = 0; ni < 8; ni++) {
        int node = n0 + ni;
        int hi = row_ptr[node + 1];
        float4 acc = {0.f, 0.f, 0.f, 0.f};
#pragma unroll 1
        for (int j0 = lo; j0 < hi; j0 += 4) {
            int j = j0 + eg;
            bool ev = (j < hi);
            int jc = ev ? j : (hi - 1);
            int s = src_sorted[jc];
            ushort4 xu = *(const ushort4*)(feat + (size_t)s * DIN + f4c * 4);
            ushort4 mu = *(const ushort4*)(emsg + (size_t)jc * DIN + f4c * 4);
            float4 xv = bf4f(xu), mv = bf4f(mu);
            float t0 = fmaxf(xv.x + mv.x, 0.f);
            float t1 = fmaxf(xv.y + mv.y, 0.f);
            float t2 = fmaxf(xv.z + mv.z, 0.f);
            float t3 = fmaxf(xv.w + mv.w, 0.f);
            if (ev && vf) {
                acc.x += t0; acc.y += t1; acc.z += t2; acc.w += t3;
            }
        }
        acc.x += __shfl_xor(acc.x, 16, 64);
        acc.y += __shfl_xor(acc.y, 16, 64);
        acc.z += __shfl_xor(acc.z, 16, 64);
        acc.w += __shfl_xor(acc.w, 16, 64);
        acc.x += __shfl_xor(acc.x, 32, 64);
        acc.y += __shfl_xor(acc.y, 32, 64);
        acc.z += __shfl_xor(acc.z, 32, 64);
        acc.w += __shfl_xor(acc.w, 32, 64);
        if (eg == 0) {
            float4 xd = {0.f, 0.f, 0.f, 0.f};
            if (vf) xd = bf4f(*(const ushort4*)(feat + (size_t)node * DIN + f4 * 4));
            float4 o = vf ? make_float4(acc.x + xd.x, acc.y + xd.y,
                                        acc.z + xd.z, acc.w + xd.w)
                          : make_float4(0.f, 0.f, 0.f, 0.f);
            ushort4 st;
            st.x = f2bf(o.x); st.y = f2bf(o.y);
            st.z = f2bf(o.z); st.w = f2bf(o.w);
            *(ushort4*)(AGGb + (size_t)node * HDIM + f4 * 4) = st;
        }
        lo = hi;
    }
}

// ---------------------------------------------------------------------------
// Gather-aggregate fallback (no emsg workspace): fused edge MLP via SGPRs.
// ---------------------------------------------------------------------------
template<int DIN>
__global__ __launch_bounds__(256) void agg_kernel(
    const unsigned short* __restrict__ feat,
    const int*   __restrict__ row_ptr,
    const int*   __restrict__ src_sorted,
    const int*   __restrict__ eid_sorted,
    const float* __restrict__ ea,
    const float* __restrict__ We,
    const float* __restrict__ be,
    unsigned short* __restrict__ AGGb)
{
    int lane = threadIdx.x & 63;
    int wv = __builtin_amdgcn_readfirstlane(blockIdx.x * 4 + (threadIdx.x >> 6));
    int n0 = wv * 8;
    if (n0 >= N_NODES) return;
    int f = lane;

    float wrow[16];
    float bias = 0.f;
    if (f < DIN) {
#pragma unroll
        for (int j = 0; j < 16; j++) wrow[j] = We[f * 16 + j];
        bias = be[f];
    } else {
#pragma unroll
        for (int j = 0; j < 16; j++) wrow[j] = 0.f;
    }

    int lo = row_ptr[n0];
    int hi = row_ptr[n0 + 8];
    int cur = 0;
    int nb = row_ptr[n0 + 1];
    float acc = 0.f;

    for (int j0 = lo; j0 < hi; j0 += 8) {
        int jn = min(8, hi - j0);
        int s[8], e[8];
#pragma unroll
        for (int k = 0; k < 8; k++) {
            int j = min(j0 + k, hi - 1);
            s[k] = src_sorted[j];
            e[k] = eid_sorted[j];
        }
        float xv[8];
#pragma unroll
        for (int k = 0; k < 8; k++)
            xv[k] = (f < DIN) ? bf2f(feat[(size_t)s[k] * DIN + f]) : 0.f;

#pragma unroll
        for (int k = 0; k < 8; k++) {
            if (k >= jn) break;
            int j = j0 + k;
            while (j >= nb) {
                float xd = (f < DIN) ? bf2f(feat[(size_t)(n0 + cur) * DIN + f]) : 0.f;
                AGGb[(size_t)(n0 + cur) * HDIM + f] = f2bf(acc + xd);
                acc = 0.f;
                cur++;
                nb = row_ptr[n0 + cur + 1];
            }
            const float4* ep = (const float4*)(ea + (size_t)e[k] * 16);
            float4 q0 = ep[0], q1 = ep[1], q2 = ep[2], q3 = ep[3];
            float a = bias;
            a = fmaf(q0.x, wrow[0],  a); a = fmaf(q0.y, wrow[1],  a);
            a = fmaf(q0.z, wrow[2],  a); a = fmaf(q0.w, wrow[3],  a);
            a = fmaf(q1.x, wrow[4],  a); a = fmaf(q1.y, wrow[5],  a);
            a = fmaf(q1.z, wrow[6],  a); a = fmaf(q1.w, wrow[7],  a);
            a = fmaf(q2.x, wrow[8],  a); a = fmaf(q2.y, wrow[9],  a);
            a = fmaf(q2.z, wrow[10], a); a = fmaf(q2.w, wrow[11], a);
            a = fmaf(q3.x, wrow[12], a); a = fmaf(q3.y, wrow[13], a);
            a = fmaf(q3.z, wrow[14], a); a = fmaf(q3.w, wrow[15], a);
            acc += fmaxf(xv[k] + a, 0.f);
        }
    }
    while (cur < 8) {
        float xd = (f < DIN) ? bf2f(feat[(size_t)(n0 + cur) * DIN + f]) : 0.f;
        AGGb[(size_t)(n0 + cur) * HDIM + f] = f2bf(acc + xd);
        acc = 0.f;
        cur++;
    }
}

// ---------------------------------------------------------------------------
// Node MFMA: Hb = bf16( leaky_relu(BN(AGGb @ W.T + b)) )
// ---------------------------------------------------------------------------
template<int DIN>
__global__ __launch_bounds__(256) void node_mfma(
    const unsigned short* __restrict__ AGGb,  // [N, 64] bf16
    unsigned short* __restrict__ Hb,          // [N, 64] bf16 out
    const float* __restrict__ W,        // [64, DIN]
    const float* __restrict__ bias,
    const float* __restrict__ gam,
    const float* __restrict__ bet,
    const float* __restrict__ mean,
    const float* __restrict__ var)
{
    int lane = threadIdx.x & 63;
    int wave = blockIdx.x * 4 + (threadIdx.x >> 6);
    if (wave >= N_NODES / 64) return;
    int n0 = wave * 64;
    int r = lane & 15;
    int g = lane >> 4;

    const short8 zero8 = (short8){0, 0, 0, 0, 0, 0, 0, 0};

    short8 zf[4][2];
#pragma unroll
    for (int nt = 0; nt < 4; nt++) {
        int node = n0 + nt * 16 + r;
        const unsigned short* ar = AGGb + (size_t)node * HDIM;
        zf[nt][0] = *(const short8*)(ar + g * 8);
        zf[nt][1] = *(const short8*)(ar + 32 + g * 8);
    }

    const float4* b4  = (const float4*)bias;
    const float4* g4  = (const float4*)gam;
    const float4* be4 = (const float4*)bet;
    const float4* m4  = (const float4*)mean;
    const float4* v4  = (const float4*)var;

#pragma unroll
    for (int ft = 0; ft < 4; ft++) {
        const float* wr = W + (size_t)(ft * 16 + r) * DIN;
        short8 af[2];
        {
            float4 w0 = *(const float4*)(wr + g * 8);
            float4 w1 = *(const float4*)(wr + g * 8 + 4);
            af[0] = cvt8(w0, w1);
            if (DIN == 64) {
                w0 = *(const float4*)(wr + 32 + g * 8);
                w1 = *(const float4*)(wr + 36 + g * 8);
                af[1] = cvt8(w0, w1);
            } else if (g == 0) {
                w0 = *(const float4*)(wr + 32);
                w1 = *(const float4*)(wr + 36);
                af[1] = cvt8(w0, w1);
            } else {
                af[1] = zero8;
            }
        }

        f32x4 acc[4];
#pragma unroll
        for (int nt = 0; nt < 4; nt++) acc[nt] = (f32x4){0.f, 0.f, 0.f, 0.f};

#pragma unroll
        for (int ks = 0; ks < 2; ks++) {
#pragma unroll
            for (int nt = 0; nt < 4; nt++) {
                acc[nt] = __builtin_amdgcn_mfma_f32_16x16x32_bf16(
                    af[ks], zf[nt][ks], acc[nt], 0, 0, 0);
            }
        }

        int idx = ft * 4 + g;
        float4 bb = b4[idx], gg = g4[idx], bt = be4[idx], mm = m4[idx], vv = v4[idx];
        float s0 = gg.x * rsqrtf(vv.x + BN_EPS);
        float s1 = gg.y * rsqrtf(vv.y + BN_EPS);
        float s2 = gg.z * rsqrtf(vv.z + BN_EPS);
        float s3 = gg.w * rsqrtf(vv.w + BN_EPS);
#pragma unroll
        for (int nt = 0; nt < 4; nt++) {
            int node = n0 + nt * 16 + r;
            float y0 = s0 * (acc[nt][0] + bb.x - mm.x) + bt.x;
            float y1 = s1 * (acc[nt][1] + bb.y - mm.y) + bt.y;
            float y2 = s2 * (acc[nt][2] + bb.z - mm.z) + bt.z;
            float y3 = s3 * (acc[nt][3] + bb.w - mm.w) + bt.w;
            y0 = (y0 > 0.f) ? y0 : 0.01f * y0;
            y1 = (y1 > 0.f) ? y1 : 0.01f * y1;
            y2 = (y2 > 0.f) ? y2 : 0.01f * y2;
            y3 = (y3 > 0.f) ? y3 : 0.01f * y3;
            union { uint2 v; unsigned int u[2]; } st;
            st.u[0] = pk2(y0, y1);
            st.u[1] = pk2(y2, y3);
            *(uint2*)(Hb + (size_t)node * HDIM + ft * 16 + g * 4) = st.v;
        }
    }
}

// ---------------------------------------------------------------------------
// Pool: hpool[batch[i]] += h3[i]  (bf16 in, f32 atomic accum; coalesced row)
// ---------------------------------------------------------------------------
__global__ __launch_bounds__(256) void pool_kernel(
    const unsigned short* __restrict__ h3b,
    const int*   __restrict__ batch,
    float*       __restrict__ hpool)
{
    int gid = blockIdx.x * 256 + threadIdx.x;
    if (gid >= N_NODES * HDIM) return;
    int i = gid >> 6, f = gid & 63;
    atomicAdd(&hpool[(size_t)batch[i] * HDIM + f], bf2f(h3b[gid]));
}

// ---------------------------------------------------------------------------
// Head v5 (R20, measured 69 us): NT=4, quarter-LDS staging, bounds (256,2).
// ---------------------------------------------------------------------------
__global__ __launch_bounds__(256, 2) void head_kernel(
    const unsigned short* __restrict__ h1b,
    const unsigned short* __restrict__ h2b,
    const unsigned short* __restrict__ h3b,
    const float* __restrict__ hpool,
    const int*   __restrict__ batch,
    const float* __restrict__ Wl1, const float* __restrict__ bl1,
    const float* __restrict__ Wl2, const float* __restrict__ bl2,
    float*       __restrict__ out)
{
    __shared__ short8 wlds[2048];    // 32 KB: one quarter (4 ft) of Wl1 fragments

    int tid = threadIdx.x;
    int lane = tid & 63;
    int wave = blockIdx.x * 4 + (tid >> 6);
    bool active = (wave < N_NODES / 64);
    int n0 = active ? wave * 64 : (N_NODES - 64);   // clamp; stores guarded
    int r = lane & 15;
    int g = lane >> 4;

    short8 zf[4][8];
#pragma unroll
    for (int nt = 0; nt < 4; nt++) {
        int node = n0 + nt * 16 + r;
        const unsigned short* r1 = h1b + (size_t)node * 64;
        const unsigned short* r2 = h2b + (size_t)node * 64;
        const unsigned short* r3 = h3b + (size_t)node * 64;
        const float* rp = hpool + (size_t)batch[node] * 64;
        zf[nt][0] = *(const short8*)(r1 + g * 8);
        zf[nt][1] = *(const short8*)(r1 + 32 + g * 8);
        zf[nt][2] = *(const short8*)(r2 + g * 8);
        zf[nt][3] = *(const short8*)(r2 + 32 + g * 8);
        zf[nt][4] = *(const short8*)(r3 + g * 8);
        zf[nt][5] = *(const short8*)(r3 + 32 + g * 8);
        const float4* q;
        q = (const float4*)(rp + g * 8);        zf[nt][6] = cvt8(q[0], q[1]);
        q = (const float4*)(rp + 32 + g * 8);   zf[nt][7] = cvt8(q[0], q[1]);
    }

    float p[4] = {0.f, 0.f, 0.f, 0.f};
    const float4* bl1_4 = (const float4*)bl1;
    const float4* wl2_4 = (const float4*)Wl2;

#pragma unroll 1
    for (int pass = 0; pass < 4; pass++) {
        if (pass) __syncthreads();           // drain previous pass before restage
#pragma unroll
        for (int i = 0; i < 8; i++) {
            int local = tid + i * 256;       // 0..2047
            int ftq = local >> 9;            // 0..3
            int ks  = (local >> 6) & 7;
            int lf  = local & 63;
            int rr = lf & 15, gg = lf >> 4;
            int ft = pass * 4 + ftq;
            const float4* q = (const float4*)(Wl1 + (size_t)(ft * 16 + rr) * 256
                                              + ks * 32 + gg * 8);
            wlds[local] = cvt8(q[0], q[1]);
        }
        __syncthreads();

#pragma unroll 1
        for (int ftq = 0; ftq < 4; ftq++) {
            int ft = pass * 4 + ftq;
            short8 af[8];
#pragma unroll
            for (int ks = 0; ks < 8; ks++) af[ks] = wlds[(ftq * 8 + ks) * 64 + lane];

            f32x4 acc[4];
#pragma unroll
            for (int nt = 0; nt < 4; nt++) acc[nt] = (f32x4){0.f, 0.f, 0.f, 0.f};
#pragma unroll
            for (int ks = 0; ks < 8; ks++) {
#pragma unroll
                for (int nt = 0; nt < 4; nt++) {
                    acc[nt] = __builtin_amdgcn_mfma_f32_16x16x32_bf16(
                        af[ks], zf[nt][ks], acc[nt], 0, 0, 0);
                }
            }

            float4 bl = bl1_4[ft * 4 + g];
            float4 w2 = wl2_4[ft * 4 + g];
#pragma unroll
            for (int nt = 0; nt < 4; nt++) {
                float a0 = acc[nt][0] + bl.x;
                float a1 = acc[nt][1] + bl.y;
                float a2 = acc[nt][2] + bl.z;
                float a3 = acc[nt][3] + bl.w;
                a0 = (a0 > 0.f) ? a0 : 0.01f * a0;
                a1 = (a1 > 0.f) ? a1 : 0.01f * a1;
                a2 = (a2 > 0.f) ? a2 : 0.01f * a2;
                a3 = (a3 > 0.f) ? a3 : 0.01f * a3;
                p[nt] += w2.x * a0 + w2.y * a1 + w2.z * a2 + w2.w * a3;
            }
        }
    }

    float b2 = bl2[0];
#pragma unroll
    for (int nt = 0; nt < 4; nt++) {
        float s = p[nt];
        s += __shfl_xor(s, 16, 64);
        s += __shfl_xor(s, 32, 64);
        if (g == 0 && active) out[n0 + nt * 16 + r] = s + b2;
    }
}

// ---------------------------------------------------------------------------
extern "C" void kernel_launch(void* const* d_in, const int* in_sizes, int n_in,
                              void* d_out, int out_size, void* d_ws, size_t ws_size,
                              hipStream_t stream) {
    const float* x     = (const float*)d_in[0];
    const int*   ei    = (const int*)  d_in[1];
    const float* ea    = (const float*)d_in[2];
    const int*   batch = (const int*)  d_in[3];

    const float* We1 = (const float*)d_in[4];  const float* be1 = (const float*)d_in[5];
    const float* W1  = (const float*)d_in[6];  const float* b1  = (const float*)d_in[7];
    const float* g1  = (const float*)d_in[8];  const float* bb1 = (const float*)d_in[9];
    const float* m1  = (const float*)d_in[10]; const float* v1  = (const float*)d_in[11];

    const float* We2 = (const float*)d_in[12]; const float* be2 = (const float*)d_in[13];
    const float* W2  = (const float*)d_in[14]; const float* b2  = (const float*)d_in[15];
    const float* g2  = (const float*)d_in[16]; const float* bb2 = (const float*)d_in[17];
    const float* m2  = (const float*)d_in[18]; const float* v2  = (const float*)d_in[19];

    const float* We3 = (const float*)d_in[20]; const float* be3 = (const float*)d_in[21];
    const float* W3  = (const float*)d_in[22]; const float* b3  = (const float*)d_in[23];
    const float* g3  = (const float*)d_in[24]; const float* bb3 = (const float*)d_in[25];
    const float* m3  = (const float*)d_in[26]; const float* v3  = (const float*)d_in[27];

    const float* Wl1 = (const float*)d_in[28]; const float* bl1 = (const float*)d_in[29];
    const float* Wl2 = (const float*)d_in[30]; const float* bl2 = (const float*)d_in[31];

    float* out = (float*)d_out;

    // ---- workspace carve-out, every buffer 256B-aligned ----
    char* wp = (char*)d_ws;
    auto carve = [&](size_t bytes) -> char* {
        char* r = wp;
        wp += (bytes + 255) & ~(size_t)255;
        return r;
    };
    unsigned short* AGGb  = (unsigned short*)carve((size_t)N_NODES * HDIM * 2);
    unsigned short* xb    = (unsigned short*)carve((size_t)N_NODES * 40 * 2);
    unsigned short* Hb1   = (unsigned short*)carve((size_t)N_NODES * HDIM * 2);
    unsigned short* Hb2   = (unsigned short*)carve((size_t)N_NODES * HDIM * 2);
    unsigned short* Hb3   = (unsigned short*)carve((size_t)N_NODES * HDIM * 2);
    float* hpool          = (float*)         carve((size_t)N_MOL * HDIM * 4);
    int* counts           = (int*)           carve((size_t)N_NODES * 4);
    int* row_ptr          = (int*)           carve((size_t)(N_NODES + 1) * 4);
    int* cursor           = (int*)           carve((size_t)N_NODES * 4);
    int* src_sorted       = (int*)           carve((size_t)N_EDGES * 4);
    int* eid_sorted       = (int*)           carve((size_t)N_EDGES * 4);
    int* block_sums       = (int*)           carve((size_t)SCAN_BLOCKS * 4);
    unsigned short* emsgA = (unsigned short*)carve((size_t)N_EDGES * HDIM * 2);  // [E,64]
    size_t need_pre       = (size_t)(wp - (char*)d_ws);
    unsigned short* em1   = (unsigned short*)carve((size_t)N_EDGES * 40 * 2);    // [E,40]
    unsigned short* em3   = (unsigned short*)carve((size_t)N_EDGES * HDIM * 2);  // [E,64]
    size_t need_fused     = (size_t)(wp - (char*)d_ws);
    bool use_fused = (ws_size >= need_fused);
    bool use_pre   = (ws_size >= need_pre);

    hipMemsetAsync(hpool, 0, (size_t)N_MOL * HDIM * sizeof(float), stream);
    hipMemsetAsync(counts, 0, (size_t)N_NODES * sizeof(int), stream);

    dim3 blk(256);
    dim3 cgrid(((size_t)N_NODES * 40 / 4 + 255) / 256);
    dim3 egrid(N_EDGES / 256);
    dim3 mgrid(EMSG_WAVES / 4);
    dim3 sgrid(SCAN_BLOCKS);
    dim3 agrid((N_NODES / 8) / 4);
    dim3 ngrid((N_NODES / 64 + 3) / 4);
    dim3 pgrid((N_NODES * HDIM) / 256);
    dim3 hgrid((N_NODES / 64 + 3) / 4);

    // ---- prep ----
    cvtx_kernel<<<cgrid, blk, 0, stream>>>(x, xb);
    hist_kernel<<<egrid, blk, 0, stream>>>(ei, counts);
    scan_phase_a<<<sgrid, blk, 0, stream>>>(counts, row_ptr, block_sums);
    scan_phase_b<<<1, 1024, 0, stream>>>(block_sums);
    scan_phase_c<<<sgrid, blk, 0, stream>>>(block_sums, row_ptr, cursor);
    scatter_kernel<<<egrid, blk, 0, stream>>>(ei, cursor, src_sorted, eid_sorted);

    if (use_fused) {
        // one gather pass computes all three layers' edge messages
        emsg_all<<<mgrid, blk, 0, stream>>>(ea, eid_sorted, We1, be1, We2, be2,
                                            We3, be3, em1, emsgA, em3);
        agg_pre<40><<<agrid, blk, 0, stream>>>(xb, row_ptr, src_sorted, em1, AGGb);
        node_mfma<40><<<ngrid, blk, 0, stream>>>(AGGb, Hb1, W1, b1, g1, bb1, m1, v1);
        agg_pre<64><<<agrid, blk, 0, stream>>>(Hb1, row_ptr, src_sorted, emsgA, AGGb);
        node_mfma<64><<<ngrid, blk, 0, stream>>>(AGGb, Hb2, W2, b2, g2, bb2, m2, v2);
        agg_pre<64><<<agrid, blk, 0, stream>>>(Hb2, row_ptr, src_sorted, em3, AGGb);
        node_mfma<64><<<ngrid, blk, 0, stream>>>(AGGb, Hb3, W3, b3, g3, bb3, m3, v3);
    } else if (use_pre) {
        emsg_mfma<40><<<mgrid, blk, 0, stream>>>(ea, eid_sorted, We1, be1, emsgA);
        agg_pre<40><<<agrid, blk, 0, stream>>>(xb, row_ptr, src_sorted, emsgA, AGGb);
        node_mfma<40><<<ngrid, blk, 0, stream>>>(AGGb, Hb1, W1, b1, g1, bb1, m1, v1);
        emsg_mfma<64><<<mgrid, blk, 0, stream>>>(ea, eid_sorted, We2, be2, emsgA);
        agg_pre<64><<<agrid, blk, 0, stream>>>(Hb1, row_ptr, src_sorted, emsgA, AGGb);
        node_mfma<64><<<ngrid, blk, 0, stream>>>(AGGb, Hb2, W2, b2, g2, bb2, m2, v2);
        emsg_mfma<64><<<mgrid, blk, 0, stream>>>(ea, eid_sorted, We3, be3, emsgA);
        agg_pre<64><<<agrid, blk, 0, stream>>>(Hb2, row_ptr, src_sorted, emsgA, AGGb);
        node_mfma<64><<<ngrid, blk, 0, stream>>>(AGGb, Hb3, W3, b3, g3, bb3, m3, v3);
    } else {
        agg_kernel<40><<<agrid, blk, 0, stream>>>(xb, row_ptr, src_sorted, eid_sorted,
                                                  ea, We1, be1, AGGb);
        node_mfma<40><<<ngrid, blk, 0, stream>>>(AGGb, Hb1, W1, b1, g1, bb1, m1, v1);
        agg_kernel<64><<<agrid, blk, 0, stream>>>(Hb1, row_ptr, src_sorted, eid_sorted,
                                                  ea, We2, be2, AGGb);
        node_mfma<64><<<ngrid, blk, 0, stream>>>(AGGb, Hb2, W2, b2, g2, bb2, m2, v2);
        agg_kernel<64><<<agrid, blk, 0, stream>>>(Hb2, row_ptr, src_sorted, eid_sorted,
                                                  ea, We3, be3, AGGb);
        node_mfma<64><<<ngrid, blk, 0, stream>>>(AGGb, Hb3, W3, b3, g3, bb3, m3, v3);
    }

    // pool
    pool_kernel<<<pgrid, blk, 0, stream>>>(Hb3, batch, hpool);
    // head
    head_kernel<<<hgrid, blk, 0, stream>>>(Hb1, Hb2, Hb3, hpool, batch,
                                           Wl1, bl1, Wl2, bl2, out);
}